// Round 1
// baseline (703.810 us; speedup 1.0000x reference)
//
#include <hip/hip_runtime.h>
#include <hip/hip_bf16.h>

// Caterpillar: N=2 T=4096 D=1024 H=8 E=4 L=32 DK=DV=64, tc=128
// Pipeline: proj GEMM -> gate/mix -> chunked scan -> window attention -> out GEMM
// R1: fp32 everywhere (bf16 only for attention LDS staging). Correctness-first baseline.

#define NB 2
#define TT 4096
#define DD 1024
#define HH 8
#define EE 4
#define LL 32
#define DKV 64
#define NT 8192   // NB*TT

using f4 = float4;

__device__ __forceinline__ ushort f2bf(float x) {
  unsigned u = __float_as_uint(x);
  u += 0x7fffu + ((u >> 16) & 1u);   // RNE
  return (ushort)(u >> 16);
}
__device__ __forceinline__ float bflo(unsigned pk) { return __uint_as_float(pk << 16); }
__device__ __forceinline__ float bfhi(unsigned pk) { return __uint_as_float(pk & 0xffff0000u); }

// ---------------- fused projection GEMM ----------------
// C[m, f] = sum_c X[m,c] * W[f,c]   (W row-major (Nc, K)), K=1024
// col-tiles: ct 0..3 -> wK/Kp, 4..7 -> wV/Vp, 8..11 -> wQ/Qp, 12 -> wG/Glin (Nc=32)
__global__ __launch_bounds__(256)
void proj_gemm(const float* __restrict__ X,
               const float* __restrict__ wK, const float* __restrict__ wV,
               const float* __restrict__ wQ, const float* __restrict__ wG,
               float* __restrict__ Kp, float* __restrict__ Vp,
               float* __restrict__ Qp, float* __restrict__ Glin)
{
  __shared__ float As[8][128];
  __shared__ float Bs[8][128];
  const int tid = threadIdx.x;
  const int tx = tid & 15, ty = tid >> 4;
  const int m0 = blockIdx.y * 128;
  const int ct = blockIdx.x;

  const float* B; float* C; int Nc, n0;
  if (ct < 12) {
    int which = ct >> 2;
    B = (which == 0) ? wK : (which == 1) ? wV : wQ;
    C = (which == 0) ? Kp : (which == 1) ? Vp : Qp;
    Nc = 512; n0 = (ct & 3) * 128;
  } else { B = wG; C = Glin; Nc = 32; n0 = 0; }
  const int ldc = Nc;

  float acc[8][8];
#pragma unroll
  for (int i = 0; i < 8; i++)
#pragma unroll
    for (int j = 0; j < 8; j++) acc[i][j] = 0.f;

  const int lr = tid >> 1;        // 0..127
  const int lk = (tid & 1) * 4;   // 0 or 4

  for (int k0 = 0; k0 < DD; k0 += 8) {
    f4 av = *(const f4*)&X[(size_t)(m0 + lr) * DD + k0 + lk];
    As[lk + 0][lr] = av.x; As[lk + 1][lr] = av.y;
    As[lk + 2][lr] = av.z; As[lk + 3][lr] = av.w;
    {
      int nrow = n0 + lr;
      f4 bv = make_float4(0.f, 0.f, 0.f, 0.f);
      if (nrow < Nc) bv = *(const f4*)&B[(size_t)nrow * DD + k0 + lk];
      Bs[lk + 0][lr] = bv.x; Bs[lk + 1][lr] = bv.y;
      Bs[lk + 2][lr] = bv.z; Bs[lk + 3][lr] = bv.w;
    }
    __syncthreads();
#pragma unroll
    for (int k = 0; k < 8; k++) {
      f4 a0 = *(const f4*)&As[k][ty * 4];
      f4 a1 = *(const f4*)&As[k][64 + ty * 4];
      f4 b0 = *(const f4*)&Bs[k][tx * 4];
      f4 b1 = *(const f4*)&Bs[k][64 + tx * 4];
      float a[8] = {a0.x, a0.y, a0.z, a0.w, a1.x, a1.y, a1.z, a1.w};
      float b[8] = {b0.x, b0.y, b0.z, b0.w, b1.x, b1.y, b1.z, b1.w};
#pragma unroll
      for (int i = 0; i < 8; i++)
#pragma unroll
        for (int j = 0; j < 8; j++) acc[i][j] = fmaf(a[i], b[j], acc[i][j]);
    }
    __syncthreads();
  }
#pragma unroll
  for (int i = 0; i < 8; i++) {
    int rm = m0 + ((i < 4) ? (ty * 4 + i) : (64 + ty * 4 + (i - 4)));
#pragma unroll
    for (int jh = 0; jh < 2; jh++) {
      int cn = n0 + jh * 64 + tx * 4;
      if (cn < Nc) {
        f4 v = make_float4(acc[i][jh * 4 + 0], acc[i][jh * 4 + 1],
                           acc[i][jh * 4 + 2], acc[i][jh * 4 + 3]);
        *(f4*)&C[(size_t)rm * ldc + cn] = v;
      }
    }
  }
}

// ---------------- output GEMM (NN): out = Y(8192x512) @ wO(512x1024) ----------------
__global__ __launch_bounds__(256)
void sgemm_nn(const float* __restrict__ A, const float* __restrict__ B,
              float* __restrict__ C)
{
  const int M_K = 512;   // inner dim
  const int Nc = 1024;
  __shared__ float As[8][128];
  __shared__ float Bs[8][128];
  const int tid = threadIdx.x;
  const int tx = tid & 15, ty = tid >> 4;
  const int m0 = blockIdx.y * 128;
  const int n0 = blockIdx.x * 128;

  float acc[8][8];
#pragma unroll
  for (int i = 0; i < 8; i++)
#pragma unroll
    for (int j = 0; j < 8; j++) acc[i][j] = 0.f;

  const int lr = tid >> 1;
  const int lk = (tid & 1) * 4;
  const int kr = tid >> 5;          // 0..7
  const int nc = (tid & 31) * 4;    // 0..124

  for (int k0 = 0; k0 < M_K; k0 += 8) {
    f4 av = *(const f4*)&A[(size_t)(m0 + lr) * M_K + k0 + lk];
    As[lk + 0][lr] = av.x; As[lk + 1][lr] = av.y;
    As[lk + 2][lr] = av.z; As[lk + 3][lr] = av.w;
    f4 bv = *(const f4*)&B[(size_t)(k0 + kr) * Nc + n0 + nc];
    *(f4*)&Bs[kr][nc] = bv;
    __syncthreads();
#pragma unroll
    for (int k = 0; k < 8; k++) {
      f4 a0 = *(const f4*)&As[k][ty * 4];
      f4 a1 = *(const f4*)&As[k][64 + ty * 4];
      f4 b0 = *(const f4*)&Bs[k][tx * 4];
      f4 b1 = *(const f4*)&Bs[k][64 + tx * 4];
      float a[8] = {a0.x, a0.y, a0.z, a0.w, a1.x, a1.y, a1.z, a1.w};
      float b[8] = {b0.x, b0.y, b0.z, b0.w, b1.x, b1.y, b1.z, b1.w};
#pragma unroll
      for (int i = 0; i < 8; i++)
#pragma unroll
        for (int j = 0; j < 8; j++) acc[i][j] = fmaf(a[i], b[j], acc[i][j]);
    }
    __syncthreads();
  }
#pragma unroll
  for (int i = 0; i < 8; i++) {
    int rm = m0 + ((i < 4) ? (ty * 4 + i) : (64 + ty * 4 + (i - 4)));
#pragma unroll
    for (int jh = 0; jh < 2; jh++) {
      int cn = n0 + jh * 64 + tx * 4;
      f4 v = make_float4(acc[i][jh * 4 + 0], acc[i][jh * 4 + 1],
                         acc[i][jh * 4 + 2], acc[i][jh * 4 + 3]);
      *(f4*)&C[(size_t)rm * Nc + cn] = v;
    }
  }
}

// ---------------- gate/mix: g=sigmoid(Glin+b); A=1-min(sum_h g,1); gK/gV = sum_h g*K/V ----------------
__global__ __launch_bounds__(256)
void gate_kernel(const float* __restrict__ Glin, const float* __restrict__ bG,
                 const float* __restrict__ Kp, const float* __restrict__ Vp,
                 float* __restrict__ gK, float* __restrict__ gV, float* __restrict__ Aout)
{
  const int nt = blockIdx.x * 4 + (threadIdx.x >> 6);
  const int lane = threadIdx.x & 63;
  const int n = nt >> 12;
  const int t = nt & 4095;

  float g[32];
  float gsum[4] = {0.f, 0.f, 0.f, 0.f};
#pragma unroll
  for (int f = 0; f < 32; f++) {
    float z = Glin[(size_t)nt * 32 + f] + bG[f];
    float s = 1.f / (1.f + __expf(-z));
    g[f] = s;
    gsum[f & 3] += s;
  }
  if (lane < 4) {
    float a = 1.f - fminf(gsum[lane], 1.f);
    Aout[(size_t)(n * 4 + lane) * 4096 + t] = a;
  }
  float gk[4] = {0.f, 0.f, 0.f, 0.f}, gv[4] = {0.f, 0.f, 0.f, 0.f};
#pragma unroll
  for (int h = 0; h < 8; h++) {
    float kv = Kp[(size_t)nt * 512 + h * 64 + lane];
    float vv = Vp[(size_t)nt * 512 + h * 64 + lane];
#pragma unroll
    for (int e = 0; e < 4; e++) {
      gk[e] = fmaf(g[h * 4 + e], kv, gk[e]);
      gv[e] = fmaf(g[h * 4 + e], vv, gv[e]);
    }
  }
#pragma unroll
  for (int e = 0; e < 4; e++) {
    size_t base = ((size_t)(n * 4 + e) * 4096 + t) * 64 + lane;
    gK[base] = gk[e];
    gV[base] = gv[e];
  }
}

// ---------------- chunked scan (in-place): state = A*state + g over c=0..127 per (n,e,l) ----------------
__global__ __launch_bounds__(64)
void scan_kernel(float* __restrict__ gX, const float* __restrict__ Aarr,
                 const float* __restrict__ initX)
{
  __shared__ float sB[128 * 64];
  __shared__ float sA[128];
  const int b = blockIdx.x;
  const int n = b >> 7, r = b & 127, e = r >> 5, l = r & 31;
  const int tbase = l * 128;
  const size_t base = ((size_t)(n * 4 + e) * 4096 + tbase) * 64;
  const int tid = threadIdx.x;  // 64 threads

  const f4* src = (const f4*)&gX[base];
#pragma unroll
  for (int q = 0; q < 32; q++)
    *(f4*)&sB[(tid + q * 64) * 4] = src[tid + q * 64];
  sA[tid]      = Aarr[(size_t)(n * 4 + e) * 4096 + tbase + tid];
  sA[64 + tid] = Aarr[(size_t)(n * 4 + e) * 4096 + tbase + 64 + tid];
  __syncthreads();

  float state = initX[((size_t)e * 32 + l) * 64 + tid];
  float* dst = &gX[base];
  for (int c = 0; c < 128; c++) {
    state = fmaf(sA[c], state, sB[c * 64 + tid]);
    dst[c * 64 + tid] = state;
  }
}

// ---------------- window attention ----------------
// block = (n,t). keys j = e*32+jj -> state s=t-31+jj (nK/nV) or init (s<0).
// scores[h][j] = q_h . uk_j / 8 ; softmax over 128; Y[h][d] = sum_j p_j uv_j[d]
__global__ __launch_bounds__(256)
void attn_kernel(const float* __restrict__ Qp, const float* __restrict__ nK,
                 const float* __restrict__ nV, const float* __restrict__ initK,
                 const float* __restrict__ initV, float* __restrict__ Y)
{
  __shared__ unsigned ukw[128 * 33];  // bf16 pairs, row stride 33 words (=66 u16)
  __shared__ unsigned uvw[128 * 33];
  __shared__ float qs[8 * 64];
  __shared__ float pbuf[8 * 128];

  const int nt = blockIdx.x;
  const int n = nt >> 12, t = nt & 4095;
  const int tid = threadIdx.x;

  {  // load/convert K,V window rows
    ushort* uk16 = (ushort*)ukw;
    ushort* uv16 = (ushort*)uvw;
    const int j = tid >> 1;
    const int e = j >> 5;
    const int jj = j & 31;
    const int s = t - 31 + jj;
    const float* srcK;
    const float* srcV;
    if (s >= 0) {
      srcK = &nK[(((size_t)(n * 4 + e) * 4096) + s) * 64];
      srcV = &nV[(((size_t)(n * 4 + e) * 4096) + s) * 64];
    } else {
      srcK = &initK[((size_t)e * 32 + (s + 32)) * 64];
      srcV = &initV[((size_t)e * 32 + (s + 32)) * 64];
    }
    const int d0 = (tid & 1) * 32;
#pragma unroll
    for (int qq = 0; qq < 8; qq++) {
      f4 kv = *(const f4*)&srcK[d0 + qq * 4];
      f4 vv = *(const f4*)&srcV[d0 + qq * 4];
      int b16 = j * 66 + d0 + qq * 4;
      uk16[b16 + 0] = f2bf(kv.x); uk16[b16 + 1] = f2bf(kv.y);
      uk16[b16 + 2] = f2bf(kv.z); uk16[b16 + 3] = f2bf(kv.w);
      uv16[b16 + 0] = f2bf(vv.x); uv16[b16 + 1] = f2bf(vv.y);
      uv16[b16 + 2] = f2bf(vv.z); uv16[b16 + 3] = f2bf(vv.w);
    }
  }
  if (tid < 128) {
    f4 qv = *(const f4*)&Qp[(size_t)nt * 512 + tid * 4];
    *(f4*)&qs[tid * 4] = qv;
  }
  __syncthreads();

  const int w = tid >> 6;
  const int lane = tid & 63;

#pragma unroll
  for (int hh = 0; hh < 2; hh++) {
    const int h = w * 2 + hh;
    const float* qh = &qs[h * 64];
    float s0 = 0.f, s1 = 0.f;
#pragma unroll
    for (int d2 = 0; d2 < 32; d2++) {
      unsigned pk0 = ukw[lane * 33 + d2];
      unsigned pk1 = ukw[(lane + 64) * 33 + d2];
      float q0 = qh[2 * d2], q1 = qh[2 * d2 + 1];
      s0 = fmaf(bflo(pk0), q0, s0); s0 = fmaf(bfhi(pk0), q1, s0);
      s1 = fmaf(bflo(pk1), q0, s1); s1 = fmaf(bfhi(pk1), q1, s1);
    }
    s0 *= 0.125f; s1 *= 0.125f;
    float m = fmaxf(s0, s1);
#pragma unroll
    for (int off = 32; off >= 1; off >>= 1) m = fmaxf(m, __shfl_xor(m, off));
    float e0 = __expf(s0 - m), e1 = __expf(s1 - m);
    float ss = e0 + e1;
#pragma unroll
    for (int off = 32; off >= 1; off >>= 1) ss += __shfl_xor(ss, off);
    float inv = 1.f / ss;
    pbuf[h * 128 + lane] = e0 * inv;
    pbuf[h * 128 + 64 + lane] = e1 * inv;
  }
  __syncthreads();

#pragma unroll
  for (int hh = 0; hh < 2; hh++) {
    const int h = w * 2 + hh;
    const float* ph = &pbuf[h * 128];
    float y = 0.f;
#pragma unroll 8
    for (int j = 0; j < 128; j++) {
      unsigned pk = uvw[j * 33 + (lane >> 1)];
      float vv = (lane & 1) ? bfhi(pk) : bflo(pk);
      y = fmaf(ph[j], vv, y);
    }
    Y[(size_t)nt * 512 + h * 64 + lane] = y;
  }
}

extern "C" void kernel_launch(void* const* d_in, const int* in_sizes, int n_in,
                              void* d_out, int out_size, void* d_ws, size_t ws_size,
                              hipStream_t stream) {
  const float* X     = (const float*)d_in[0];
  const float* wG    = (const float*)d_in[1];
  const float* bG    = (const float*)d_in[2];
  const float* wK    = (const float*)d_in[3];
  const float* wV    = (const float*)d_in[4];
  const float* wQ    = (const float*)d_in[5];
  const float* wO    = (const float*)d_in[6];
  const float* initK = (const float*)d_in[7];
  const float* initV = (const float*)d_in[8];
  float* out = (float*)d_out;

  float* ws   = (float*)d_ws;
  float* Glin = ws;                  // 8192*32
  float* Kp   = Glin + 262144;       // 8192*512
  float* Vp   = Kp + 4194304;        // 8192*512
  float* Qp   = Vp + 4194304;        // 8192*512
  float* gK   = Qp + 4194304;        // 2*4*4096*64
  float* gV   = gK + 2097152;
  float* Aarr = gV + 2097152;        // 2*4*4096
  float* Ybuf = Kp;                  // alias: Kp dead after gate_kernel

  proj_gemm<<<dim3(13, 64), 256, 0, stream>>>(X, wK, wV, wQ, wG, Kp, Vp, Qp, Glin);
  gate_kernel<<<2048, 256, 0, stream>>>(Glin, bG, Kp, Vp, gK, gV, Aarr);
  scan_kernel<<<256, 64, 0, stream>>>(gK, Aarr, initK);
  scan_kernel<<<256, 64, 0, stream>>>(gV, Aarr, initV);
  attn_kernel<<<8192, 256, 0, stream>>>(Qp, gK, gV, initK, initV, Ybuf);
  sgemm_nn<<<dim3(8, 64), 256, 0, stream>>>(Ybuf, wO, out);
}

// Round 2
// 314.487 us; speedup vs baseline: 2.2380x; 2.2380x over previous
//
#include <hip/hip_runtime.h>
#include <hip/hip_bf16.h>

// Caterpillar: N=2 T=4096 D=1024 H=8 E=4 L=32 DK=DV=64
// R2: bf16 MFMA for both GEMMs (m97 structure: 128^2 tile, global_load_lds w=16,
//     2-barrier K-loop). Everything else fp32 as in the passing R1 baseline.

using f4 = float4;
typedef __attribute__((ext_vector_type(8))) short short8;   // 8 bf16 (4 VGPRs)
typedef __attribute__((ext_vector_type(4))) float floatx4;  // 4 fp32 acc

__device__ __forceinline__ ushort f2bf(float x) {
  unsigned u = __float_as_uint(x);
  u += 0x7fffu + ((u >> 16) & 1u);   // RNE
  return (ushort)(u >> 16);
}
__device__ __forceinline__ float bflo(unsigned pk) { return __uint_as_float(pk << 16); }
__device__ __forceinline__ float bfhi(unsigned pk) { return __uint_as_float(pk & 0xffff0000u); }

__device__ __forceinline__ void gll16(const void* g, void* l) {
  __builtin_amdgcn_global_load_lds((const __attribute__((address_space(1))) void*)g,
                                   (__attribute__((address_space(3))) void*)l, 16, 0, 0);
}

// ---------------- conversions ----------------
__global__ __launch_bounds__(256)
void conv_f32_bf16(const float* __restrict__ src, ushort* __restrict__ dst, int n4) {
  for (int i = blockIdx.x * blockDim.x + threadIdx.x; i < n4; i += gridDim.x * blockDim.x) {
    f4 v = ((const f4*)src)[i];
    ushort4 o; o.x = f2bf(v.x); o.y = f2bf(v.y); o.z = f2bf(v.z); o.w = f2bf(v.w);
    ((ushort4*)dst)[i] = o;
  }
}

// wAll rows: [0,512)=wK, [512,1024)=wV, [1024,1536)=wQ, [1536,1568)=wG, [1568,1664)=0
__global__ __launch_bounds__(256)
void conv_weights(const float* __restrict__ wK, const float* __restrict__ wV,
                  const float* __restrict__ wQ, const float* __restrict__ wG,
                  ushort* __restrict__ wAll) {
  int i4 = blockIdx.x * 256 + threadIdx.x;     // 0..425983
  int idx = i4 * 4;
  int row = idx >> 10;
  f4 v = make_float4(0.f, 0.f, 0.f, 0.f);
  if (row < 512)       v = *(const f4*)&wK[idx];
  else if (row < 1024) v = *(const f4*)&wV[idx - 524288];
  else if (row < 1536) v = *(const f4*)&wQ[idx - 1048576];
  else if (row < 1568) v = *(const f4*)&wG[idx - 1572864];
  ushort4 o; o.x = f2bf(v.x); o.y = f2bf(v.y); o.z = f2bf(v.z); o.w = f2bf(v.w);
  *(ushort4*)&wAll[idx] = o;
}

// wObf[n][k] = wO[k][n]  (wO is (512,1024) row-major)
__global__ __launch_bounds__(256)
void transpose_wO(const float* __restrict__ wO, ushort* __restrict__ wObf) {
  int i = blockIdx.x * 256 + threadIdx.x;      // 0..524287
  int n = i >> 9, k = i & 511;
  wObf[i] = f2bf(wO[(size_t)k * 1024 + n]);
}

// ---------------- projection GEMM (bf16 MFMA) ----------------
// C[m,f] = sum_k Xbf[m,k] * wAll[f,k] ; 13 col-tiles (K,V,Q x4 + G)
__global__ __launch_bounds__(256)
void proj_gemm_mfma(const ushort* __restrict__ Xbf, const ushort* __restrict__ wAll,
                    float* __restrict__ Kp, float* __restrict__ Vp,
                    float* __restrict__ Qp, float* __restrict__ Glin)
{
  __shared__ ushort As[4096];   // 128 rows x 32 (k-contiguous)
  __shared__ ushort Bs[4096];
  const int tid = threadIdx.x;
  const int m0 = blockIdx.y * 128;
  const int ct = blockIdx.x;

  float* C; int Nc, n0;
  if (ct < 12) {
    int which = ct >> 2;
    C = (which == 0) ? Kp : (which == 1) ? Vp : Qp;
    Nc = 512; n0 = (ct & 3) * 128;
  } else { C = Glin; Nc = 32; n0 = 0; }

  const int lane = tid & 63;
  const int wv = tid >> 6;
  const int wm = (wv >> 1) * 64, wn = (wv & 1) * 64;

  const int srow = tid >> 2, scol = (tid & 3) * 8;
  const ushort* gA = Xbf  + (size_t)(m0 + srow) * 1024 + scol;
  const ushort* gB = wAll + (size_t)(ct * 128 + srow) * 1024 + scol;
  ushort* lA0 = &As[tid * 8]; ushort* lA1 = &As[2048 + tid * 8];
  ushort* lB0 = &Bs[tid * 8]; ushort* lB1 = &Bs[2048 + tid * 8];

  floatx4 acc[4][4];
#pragma unroll
  for (int i = 0; i < 4; i++)
#pragma unroll
    for (int j = 0; j < 4; j++) acc[i][j] = (floatx4){0.f, 0.f, 0.f, 0.f};

  const int fr = lane & 15;
  const int fk = (lane >> 4) * 8;
  const short8* pA[4]; const short8* pB[4];
#pragma unroll
  for (int i = 0; i < 4; i++) {
    pA[i] = (const short8*)&As[(wm + i * 16 + fr) * 32 + fk];
    pB[i] = (const short8*)&Bs[(wn + i * 16 + fr) * 32 + fk];
  }

  for (int k0 = 0; k0 < 1024; k0 += 32) {
    gll16(gA + k0, lA0);
    gll16(gA + 65536 + k0, lA1);   // rows +64
    gll16(gB + k0, lB0);
    gll16(gB + 65536 + k0, lB1);
    __syncthreads();
    short8 a[4], b[4];
#pragma unroll
    for (int i = 0; i < 4; i++) { a[i] = *pA[i]; b[i] = *pB[i]; }
#pragma unroll
    for (int mi = 0; mi < 4; mi++)
#pragma unroll
      for (int ni = 0; ni < 4; ni++)
        acc[mi][ni] = __builtin_amdgcn_mfma_f32_16x16x32_bf16(a[mi], b[ni], acc[mi][ni], 0, 0, 0);
    __syncthreads();
  }

  const int fq = lane >> 4;
#pragma unroll
  for (int mi = 0; mi < 4; mi++) {
    int row = m0 + wm + mi * 16 + fq * 4;
#pragma unroll
    for (int ni = 0; ni < 4; ni++) {
      int col = n0 + wn + ni * 16 + fr;
      if (col < Nc) {
#pragma unroll
        for (int j = 0; j < 4; j++)
          C[(size_t)(row + j) * Nc + col] = acc[mi][ni][j];
      }
    }
  }
}

// ---------------- output GEMM (bf16 MFMA): out = Ybf(8192x512) @ wObf^T ----------------
__global__ __launch_bounds__(256)
void out_gemm_mfma(const ushort* __restrict__ Ybf, const ushort* __restrict__ wObf,
                   float* __restrict__ out)
{
  __shared__ ushort As[4096];
  __shared__ ushort Bs[4096];
  const int tid = threadIdx.x;
  const int m0 = blockIdx.y * 128;
  const int n0 = blockIdx.x * 128;
  const int lane = tid & 63;
  const int wv = tid >> 6;
  const int wm = (wv >> 1) * 64, wn = (wv & 1) * 64;

  const int srow = tid >> 2, scol = (tid & 3) * 8;
  const ushort* gA = Ybf  + (size_t)(m0 + srow) * 512 + scol;
  const ushort* gB = wObf + (size_t)(n0 + srow) * 512 + scol;
  ushort* lA0 = &As[tid * 8]; ushort* lA1 = &As[2048 + tid * 8];
  ushort* lB0 = &Bs[tid * 8]; ushort* lB1 = &Bs[2048 + tid * 8];

  floatx4 acc[4][4];
#pragma unroll
  for (int i = 0; i < 4; i++)
#pragma unroll
    for (int j = 0; j < 4; j++) acc[i][j] = (floatx4){0.f, 0.f, 0.f, 0.f};

  const int fr = lane & 15;
  const int fk = (lane >> 4) * 8;
  const short8* pA[4]; const short8* pB[4];
#pragma unroll
  for (int i = 0; i < 4; i++) {
    pA[i] = (const short8*)&As[(wm + i * 16 + fr) * 32 + fk];
    pB[i] = (const short8*)&Bs[(wn + i * 16 + fr) * 32 + fk];
  }

  for (int k0 = 0; k0 < 512; k0 += 32) {
    gll16(gA + k0, lA0);
    gll16(gA + 32768 + k0, lA1);   // rows +64 (stride 512)
    gll16(gB + k0, lB0);
    gll16(gB + 32768 + k0, lB1);
    __syncthreads();
    short8 a[4], b[4];
#pragma unroll
    for (int i = 0; i < 4; i++) { a[i] = *pA[i]; b[i] = *pB[i]; }
#pragma unroll
    for (int mi = 0; mi < 4; mi++)
#pragma unroll
      for (int ni = 0; ni < 4; ni++)
        acc[mi][ni] = __builtin_amdgcn_mfma_f32_16x16x32_bf16(a[mi], b[ni], acc[mi][ni], 0, 0, 0);
    __syncthreads();
  }

  const int fq = lane >> 4;
#pragma unroll
  for (int mi = 0; mi < 4; mi++) {
    int row = m0 + wm + mi * 16 + fq * 4;
#pragma unroll
    for (int ni = 0; ni < 4; ni++) {
      int col = n0 + wn + ni * 16 + fr;
#pragma unroll
      for (int j = 0; j < 4; j++)
        out[(size_t)(row + j) * 1024 + col] = acc[mi][ni][j];
    }
  }
}

// ---------------- gate/mix ----------------
__global__ __launch_bounds__(256)
void gate_kernel(const float* __restrict__ Glin, const float* __restrict__ bG,
                 const float* __restrict__ Kp, const float* __restrict__ Vp,
                 float* __restrict__ gK, float* __restrict__ gV, float* __restrict__ Aout)
{
  const int nt = blockIdx.x * 4 + (threadIdx.x >> 6);
  const int lane = threadIdx.x & 63;
  const int n = nt >> 12;
  const int t = nt & 4095;

  float g[32];
  float gsum[4] = {0.f, 0.f, 0.f, 0.f};
#pragma unroll
  for (int f = 0; f < 32; f++) {
    float z = Glin[(size_t)nt * 32 + f] + bG[f];
    float s = 1.f / (1.f + __expf(-z));
    g[f] = s;
    gsum[f & 3] += s;
  }
  if (lane < 4) {
    float a = 1.f - fminf(gsum[lane], 1.f);
    Aout[(size_t)(n * 4 + lane) * 4096 + t] = a;
  }
  float gk[4] = {0.f, 0.f, 0.f, 0.f}, gv[4] = {0.f, 0.f, 0.f, 0.f};
#pragma unroll
  for (int h = 0; h < 8; h++) {
    float kv = Kp[(size_t)nt * 512 + h * 64 + lane];
    float vv = Vp[(size_t)nt * 512 + h * 64 + lane];
#pragma unroll
    for (int e = 0; e < 4; e++) {
      gk[e] = fmaf(g[h * 4 + e], kv, gk[e]);
      gv[e] = fmaf(g[h * 4 + e], vv, gv[e]);
    }
  }
#pragma unroll
  for (int e = 0; e < 4; e++) {
    size_t base = ((size_t)(n * 4 + e) * 4096 + t) * 64 + lane;
    gK[base] = gk[e];
    gV[base] = gv[e];
  }
}

// ---------------- chunked scan (both K and V in one launch) ----------------
__global__ __launch_bounds__(64)
void scan_kernel(float* __restrict__ gK, float* __restrict__ gV,
                 const float* __restrict__ Aarr,
                 const float* __restrict__ initK, const float* __restrict__ initV)
{
  __shared__ float sB[128 * 64];
  __shared__ float sA[128];
  const int b = blockIdx.x;
  const int half = b >> 8, sub = b & 255;
  float* gX = half ? gV : gK;
  const float* initX = half ? initV : initK;
  const int n = sub >> 7, r = sub & 127, e = r >> 5, l = r & 31;
  const int tbase = l * 128;
  const size_t base = ((size_t)(n * 4 + e) * 4096 + tbase) * 64;
  const int tid = threadIdx.x;

  const f4* src = (const f4*)&gX[base];
#pragma unroll
  for (int q = 0; q < 32; q++)
    *(f4*)&sB[(tid + q * 64) * 4] = src[tid + q * 64];
  sA[tid]      = Aarr[(size_t)(n * 4 + e) * 4096 + tbase + tid];
  sA[64 + tid] = Aarr[(size_t)(n * 4 + e) * 4096 + tbase + 64 + tid];
  __syncthreads();

  float state = initX[((size_t)e * 32 + l) * 64 + tid];
  float* dst = &gX[base];
  for (int c = 0; c < 128; c++) {
    state = fmaf(sA[c], state, sB[c * 64 + tid]);
    dst[c * 64 + tid] = state;
  }
}

// ---------------- window attention (writes bf16 Y) ----------------
__global__ __launch_bounds__(256)
void attn_kernel(const float* __restrict__ Qp, const float* __restrict__ nK,
                 const float* __restrict__ nV, const float* __restrict__ initK,
                 const float* __restrict__ initV, ushort* __restrict__ Y)
{
  __shared__ unsigned ukw[128 * 33];
  __shared__ unsigned uvw[128 * 33];
  __shared__ float qs[8 * 64];
  __shared__ float pbuf[8 * 128];

  const int nt = blockIdx.x;
  const int n = nt >> 12, t = nt & 4095;
  const int tid = threadIdx.x;

  {
    ushort* uk16 = (ushort*)ukw;
    ushort* uv16 = (ushort*)uvw;
    const int j = tid >> 1;
    const int e = j >> 5;
    const int jj = j & 31;
    const int s = t - 31 + jj;
    const float* srcK;
    const float* srcV;
    if (s >= 0) {
      srcK = &nK[(((size_t)(n * 4 + e) * 4096) + s) * 64];
      srcV = &nV[(((size_t)(n * 4 + e) * 4096) + s) * 64];
    } else {
      srcK = &initK[((size_t)e * 32 + (s + 32)) * 64];
      srcV = &initV[((size_t)e * 32 + (s + 32)) * 64];
    }
    const int d0 = (tid & 1) * 32;
#pragma unroll
    for (int qq = 0; qq < 8; qq++) {
      f4 kv = *(const f4*)&srcK[d0 + qq * 4];
      f4 vv = *(const f4*)&srcV[d0 + qq * 4];
      int b16 = j * 66 + d0 + qq * 4;
      uk16[b16 + 0] = f2bf(kv.x); uk16[b16 + 1] = f2bf(kv.y);
      uk16[b16 + 2] = f2bf(kv.z); uk16[b16 + 3] = f2bf(kv.w);
      uv16[b16 + 0] = f2bf(vv.x); uv16[b16 + 1] = f2bf(vv.y);
      uv16[b16 + 2] = f2bf(vv.z); uv16[b16 + 3] = f2bf(vv.w);
    }
  }
  if (tid < 128) {
    f4 qv = *(const f4*)&Qp[(size_t)nt * 512 + tid * 4];
    *(f4*)&qs[tid * 4] = qv;
  }
  __syncthreads();

  const int w = tid >> 6;
  const int lane = tid & 63;

#pragma unroll
  for (int hh = 0; hh < 2; hh++) {
    const int h = w * 2 + hh;
    const float* qh = &qs[h * 64];
    float s0 = 0.f, s1 = 0.f;
#pragma unroll
    for (int d2 = 0; d2 < 32; d2++) {
      unsigned pk0 = ukw[lane * 33 + d2];
      unsigned pk1 = ukw[(lane + 64) * 33 + d2];
      float q0 = qh[2 * d2], q1 = qh[2 * d2 + 1];
      s0 = fmaf(bflo(pk0), q0, s0); s0 = fmaf(bfhi(pk0), q1, s0);
      s1 = fmaf(bflo(pk1), q0, s1); s1 = fmaf(bfhi(pk1), q1, s1);
    }
    s0 *= 0.125f; s1 *= 0.125f;
    float m = fmaxf(s0, s1);
#pragma unroll
    for (int off = 32; off >= 1; off >>= 1) m = fmaxf(m, __shfl_xor(m, off));
    float e0 = __expf(s0 - m), e1 = __expf(s1 - m);
    float ss = e0 + e1;
#pragma unroll
    for (int off = 32; off >= 1; off >>= 1) ss += __shfl_xor(ss, off);
    float inv = 1.f / ss;
    pbuf[h * 128 + lane] = e0 * inv;
    pbuf[h * 128 + 64 + lane] = e1 * inv;
  }
  __syncthreads();

#pragma unroll
  for (int hh = 0; hh < 2; hh++) {
    const int h = w * 2 + hh;
    const float* ph = &pbuf[h * 128];
    float y = 0.f;
#pragma unroll 8
    for (int j = 0; j < 128; j++) {
      unsigned pk = uvw[j * 33 + (lane >> 1)];
      float vv = (lane & 1) ? bfhi(pk) : bflo(pk);
      y = fmaf(ph[j], vv, y);
    }
    Y[(size_t)nt * 512 + h * 64 + lane] = f2bf(y);
  }
}

extern "C" void kernel_launch(void* const* d_in, const int* in_sizes, int n_in,
                              void* d_out, int out_size, void* d_ws, size_t ws_size,
                              hipStream_t stream) {
  const float* X     = (const float*)d_in[0];
  const float* wG    = (const float*)d_in[1];
  const float* bG    = (const float*)d_in[2];
  const float* wK    = (const float*)d_in[3];
  const float* wV    = (const float*)d_in[4];
  const float* wQ    = (const float*)d_in[5];
  const float* wO    = (const float*)d_in[6];
  const float* initK = (const float*)d_in[7];
  const float* initV = (const float*)d_in[8];
  float* out = (float*)d_out;

  float* ws = (float*)d_ws;
  // region 0: Xbf (16MB) -> later gK(8MB)+gV(8MB)
  ushort* Xbf  = (ushort*)(ws + 0);
  float*  gK   = ws + 0;
  float*  gV   = ws + 2097152;
  ushort* wAll = (ushort*)(ws + 4194304);     // 1664x1024 bf16
  ushort* wObf = (ushort*)(ws + 5046272);     // 1024x512 bf16
  float*  Glin = ws + 5308416;                // 8192x32
  float*  Kp   = ws + 5570560;                // 8192x512 -> later Ybf (bf16)
  ushort* Ybf  = (ushort*)Kp;
  float*  Vp   = ws + 9764864;
  float*  Qp   = ws + 13959168;
  float*  Aarr = ws + 18153472;               // 2*4*4096

  conv_f32_bf16<<<2048, 256, 0, stream>>>(X, Xbf, 2097152);
  conv_weights<<<1664, 256, 0, stream>>>(wK, wV, wQ, wG, wAll);
  transpose_wO<<<2048, 256, 0, stream>>>(wO, wObf);
  proj_gemm_mfma<<<dim3(13, 64), 256, 0, stream>>>(Xbf, wAll, Kp, Vp, Qp, Glin);
  gate_kernel<<<2048, 256, 0, stream>>>(Glin, bG, Kp, Vp, gK, gV, Aarr);
  scan_kernel<<<512, 64, 0, stream>>>(gK, gV, Aarr, initK, initV);
  attn_kernel<<<8192, 256, 0, stream>>>(Qp, gK, gV, initK, initV, Ybf);
  out_gemm_mfma<<<dim3(8, 64), 256, 0, stream>>>(Ybf, wObf, out);
}

// Round 4
// 226.548 us; speedup vs baseline: 3.1067x; 1.3882x over previous
//
#include <hip/hip_runtime.h>
#include <hip/hip_bf16.h>

// Caterpillar: N=2 T=4096 D=1024 H=8 E=4 L=32 DK=DV=64
// R3 (resubmit; prior round was GPUAcquisitionTimeout): MFMA window-attention
// (chunked dense-band, online softmax, swizzled LDS). GEMMs unchanged from R2.

using f4 = float4;
typedef __attribute__((ext_vector_type(8))) short short8;   // 8 bf16
typedef __attribute__((ext_vector_type(4))) float floatx4;  // 4 fp32 acc

__device__ __forceinline__ ushort f2bf(float x) {
  unsigned u = __float_as_uint(x);
  u += 0x7fffu + ((u >> 16) & 1u);   // RNE
  return (ushort)(u >> 16);
}
__device__ __forceinline__ unsigned pk2(float lo, float hi) {
  return (unsigned)f2bf(lo) | ((unsigned)f2bf(hi) << 16);
}
__device__ __forceinline__ float bflo(unsigned pk) { return __uint_as_float(pk << 16); }
__device__ __forceinline__ float bfhi(unsigned pk) { return __uint_as_float(pk & 0xffff0000u); }

__device__ __forceinline__ void gll16(const void* g, void* l) {
  __builtin_amdgcn_global_load_lds((const __attribute__((address_space(1))) void*)g,
                                   (__attribute__((address_space(3))) void*)l, 16, 0, 0);
}

// ---------------- conversions ----------------
__global__ __launch_bounds__(256)
void conv_f32_bf16(const float* __restrict__ src, ushort* __restrict__ dst, int n4) {
  for (int i = blockIdx.x * blockDim.x + threadIdx.x; i < n4; i += gridDim.x * blockDim.x) {
    f4 v = ((const f4*)src)[i];
    ushort4 o; o.x = f2bf(v.x); o.y = f2bf(v.y); o.z = f2bf(v.z); o.w = f2bf(v.w);
    ((ushort4*)dst)[i] = o;
  }
}

__global__ __launch_bounds__(256)
void conv_weights(const float* __restrict__ wK, const float* __restrict__ wV,
                  const float* __restrict__ wQ, const float* __restrict__ wG,
                  ushort* __restrict__ wAll) {
  int i4 = blockIdx.x * 256 + threadIdx.x;
  int idx = i4 * 4;
  int row = idx >> 10;
  f4 v = make_float4(0.f, 0.f, 0.f, 0.f);
  if (row < 512)       v = *(const f4*)&wK[idx];
  else if (row < 1024) v = *(const f4*)&wV[idx - 524288];
  else if (row < 1536) v = *(const f4*)&wQ[idx - 1048576];
  else if (row < 1568) v = *(const f4*)&wG[idx - 1572864];
  ushort4 o; o.x = f2bf(v.x); o.y = f2bf(v.y); o.z = f2bf(v.z); o.w = f2bf(v.w);
  *(ushort4*)&wAll[idx] = o;
}

__global__ __launch_bounds__(256)
void transpose_wO(const float* __restrict__ wO, ushort* __restrict__ wObf) {
  int i = blockIdx.x * 256 + threadIdx.x;
  int n = i >> 9, k = i & 511;
  wObf[i] = f2bf(wO[(size_t)k * 1024 + n]);
}

// ---------------- projection GEMM (bf16 MFMA) ----------------
__global__ __launch_bounds__(256)
void proj_gemm_mfma(const ushort* __restrict__ Xbf, const ushort* __restrict__ wAll,
                    float* __restrict__ Kp, float* __restrict__ Vp,
                    float* __restrict__ Qp, float* __restrict__ Glin)
{
  __shared__ ushort As[4096];
  __shared__ ushort Bs[4096];
  const int tid = threadIdx.x;
  const int m0 = blockIdx.y * 128;
  const int ct = blockIdx.x;

  float* C; int Nc, n0;
  if (ct < 12) {
    int which = ct >> 2;
    C = (which == 0) ? Kp : (which == 1) ? Vp : Qp;
    Nc = 512; n0 = (ct & 3) * 128;
  } else { C = Glin; Nc = 32; n0 = 0; }

  const int lane = tid & 63;
  const int wv = tid >> 6;
  const int wm = (wv >> 1) * 64, wn = (wv & 1) * 64;

  const int srow = tid >> 2, scol = (tid & 3) * 8;
  const ushort* gA = Xbf  + (size_t)(m0 + srow) * 1024 + scol;
  const ushort* gB = wAll + (size_t)(ct * 128 + srow) * 1024 + scol;
  ushort* lA0 = &As[tid * 8]; ushort* lA1 = &As[2048 + tid * 8];
  ushort* lB0 = &Bs[tid * 8]; ushort* lB1 = &Bs[2048 + tid * 8];

  floatx4 acc[4][4];
#pragma unroll
  for (int i = 0; i < 4; i++)
#pragma unroll
    for (int j = 0; j < 4; j++) acc[i][j] = (floatx4){0.f, 0.f, 0.f, 0.f};

  const int fr = lane & 15;
  const int fk = (lane >> 4) * 8;
  const short8* pA[4]; const short8* pB[4];
#pragma unroll
  for (int i = 0; i < 4; i++) {
    pA[i] = (const short8*)&As[(wm + i * 16 + fr) * 32 + fk];
    pB[i] = (const short8*)&Bs[(wn + i * 16 + fr) * 32 + fk];
  }

  for (int k0 = 0; k0 < 1024; k0 += 32) {
    gll16(gA + k0, lA0);
    gll16(gA + 65536 + k0, lA1);
    gll16(gB + k0, lB0);
    gll16(gB + 65536 + k0, lB1);
    __syncthreads();
    short8 a[4], b[4];
#pragma unroll
    for (int i = 0; i < 4; i++) { a[i] = *pA[i]; b[i] = *pB[i]; }
#pragma unroll
    for (int mi = 0; mi < 4; mi++)
#pragma unroll
      for (int ni = 0; ni < 4; ni++)
        acc[mi][ni] = __builtin_amdgcn_mfma_f32_16x16x32_bf16(a[mi], b[ni], acc[mi][ni], 0, 0, 0);
    __syncthreads();
  }

  const int fq = lane >> 4;
#pragma unroll
  for (int mi = 0; mi < 4; mi++) {
    int row = m0 + wm + mi * 16 + fq * 4;
#pragma unroll
    for (int ni = 0; ni < 4; ni++) {
      int col = n0 + wn + ni * 16 + fr;
      if (col < Nc) {
#pragma unroll
        for (int j = 0; j < 4; j++)
          C[(size_t)(row + j) * Nc + col] = acc[mi][ni][j];
      }
    }
  }
}

// ---------------- output GEMM (bf16 MFMA) ----------------
__global__ __launch_bounds__(256)
void out_gemm_mfma(const ushort* __restrict__ Ybf, const ushort* __restrict__ wObf,
                   float* __restrict__ out)
{
  __shared__ ushort As[4096];
  __shared__ ushort Bs[4096];
  const int tid = threadIdx.x;
  const int m0 = blockIdx.y * 128;
  const int n0 = blockIdx.x * 128;
  const int lane = tid & 63;
  const int wv = tid >> 6;
  const int wm = (wv >> 1) * 64, wn = (wv & 1) * 64;

  const int srow = tid >> 2, scol = (tid & 3) * 8;
  const ushort* gA = Ybf  + (size_t)(m0 + srow) * 512 + scol;
  const ushort* gB = wObf + (size_t)(n0 + srow) * 512 + scol;
  ushort* lA0 = &As[tid * 8]; ushort* lA1 = &As[2048 + tid * 8];
  ushort* lB0 = &Bs[tid * 8]; ushort* lB1 = &Bs[2048 + tid * 8];

  floatx4 acc[4][4];
#pragma unroll
  for (int i = 0; i < 4; i++)
#pragma unroll
    for (int j = 0; j < 4; j++) acc[i][j] = (floatx4){0.f, 0.f, 0.f, 0.f};

  const int fr = lane & 15;
  const int fk = (lane >> 4) * 8;
  const short8* pA[4]; const short8* pB[4];
#pragma unroll
  for (int i = 0; i < 4; i++) {
    pA[i] = (const short8*)&As[(wm + i * 16 + fr) * 32 + fk];
    pB[i] = (const short8*)&Bs[(wn + i * 16 + fr) * 32 + fk];
  }

  for (int k0 = 0; k0 < 512; k0 += 32) {
    gll16(gA + k0, lA0);
    gll16(gA + 32768 + k0, lA1);
    gll16(gB + k0, lB0);
    gll16(gB + 32768 + k0, lB1);
    __syncthreads();
    short8 a[4], b[4];
#pragma unroll
    for (int i = 0; i < 4; i++) { a[i] = *pA[i]; b[i] = *pB[i]; }
#pragma unroll
    for (int mi = 0; mi < 4; mi++)
#pragma unroll
      for (int ni = 0; ni < 4; ni++)
        acc[mi][ni] = __builtin_amdgcn_mfma_f32_16x16x32_bf16(a[mi], b[ni], acc[mi][ni], 0, 0, 0);
    __syncthreads();
  }

  const int fq = lane >> 4;
#pragma unroll
  for (int mi = 0; mi < 4; mi++) {
    int row = m0 + wm + mi * 16 + fq * 4;
#pragma unroll
    for (int ni = 0; ni < 4; ni++) {
      int col = n0 + wn + ni * 16 + fr;
#pragma unroll
      for (int j = 0; j < 4; j++)
        out[(size_t)(row + j) * 1024 + col] = acc[mi][ni][j];
    }
  }
}

// ---------------- gate/mix ----------------
__global__ __launch_bounds__(256)
void gate_kernel(const float* __restrict__ Glin, const float* __restrict__ bG,
                 const float* __restrict__ Kp, const float* __restrict__ Vp,
                 float* __restrict__ gK, float* __restrict__ gV, float* __restrict__ Aout)
{
  const int nt = blockIdx.x * 4 + (threadIdx.x >> 6);
  const int lane = threadIdx.x & 63;
  const int n = nt >> 12;
  const int t = nt & 4095;

  float g[32];
  float gsum[4] = {0.f, 0.f, 0.f, 0.f};
#pragma unroll
  for (int f = 0; f < 32; f++) {
    float z = Glin[(size_t)nt * 32 + f] + bG[f];
    float s = 1.f / (1.f + __expf(-z));
    g[f] = s;
    gsum[f & 3] += s;
  }
  if (lane < 4) {
    float a = 1.f - fminf(gsum[lane], 1.f);
    Aout[(size_t)(n * 4 + lane) * 4096 + t] = a;
  }
  float gk[4] = {0.f, 0.f, 0.f, 0.f}, gv[4] = {0.f, 0.f, 0.f, 0.f};
#pragma unroll
  for (int h = 0; h < 8; h++) {
    float kv = Kp[(size_t)nt * 512 + h * 64 + lane];
    float vv = Vp[(size_t)nt * 512 + h * 64 + lane];
#pragma unroll
    for (int e = 0; e < 4; e++) {
      gk[e] = fmaf(g[h * 4 + e], kv, gk[e]);
      gv[e] = fmaf(g[h * 4 + e], vv, gv[e]);
    }
  }
#pragma unroll
  for (int e = 0; e < 4; e++) {
    size_t base = ((size_t)(n * 4 + e) * 4096 + t) * 64 + lane;
    gK[base] = gk[e];
    gV[base] = gv[e];
  }
}

// ---------------- chunked scan ----------------
__global__ __launch_bounds__(64)
void scan_kernel(float* __restrict__ gK, float* __restrict__ gV,
                 const float* __restrict__ Aarr,
                 const float* __restrict__ initK, const float* __restrict__ initV)
{
  __shared__ float sB[128 * 64];
  __shared__ float sA[128];
  const int b = blockIdx.x;
  const int half = b >> 8, sub = b & 255;
  float* gX = half ? gV : gK;
  const float* initX = half ? initV : initK;
  const int n = sub >> 7, r = sub & 127, e = r >> 5, l = r & 31;
  const int tbase = l * 128;
  const size_t base = ((size_t)(n * 4 + e) * 4096 + tbase) * 64;
  const int tid = threadIdx.x;

  const f4* src = (const f4*)&gX[base];
#pragma unroll
  for (int q = 0; q < 32; q++)
    *(f4*)&sB[(tid + q * 64) * 4] = src[tid + q * 64];
  sA[tid]      = Aarr[(size_t)(n * 4 + e) * 4096 + tbase + tid];
  sA[64 + tid] = Aarr[(size_t)(n * 4 + e) * 4096 + tbase + 64 + tid];
  __syncthreads();

  float state = initX[((size_t)e * 32 + l) * 64 + tid];
  float* dst = &gX[base];
  for (int c = 0; c < 128; c++) {
    state = fmaf(sA[c], state, sB[c * 64 + tid]);
    dst[c * 64 + tid] = state;
  }
}

// ---------------- MFMA window attention ----------------
// block = (n, chunk of 32 queries). t = c*32+i. keys per e: states s = t0-31+u,
// u in [0,63); u==63 zero-pad. valid iff (u - i) in [0,32).
// rows m = h*32+i (256); wave w owns m in [64w, 64w+64).
__global__ __launch_bounds__(256, 1)
void attn_mfma(const float* __restrict__ Qp, const float* __restrict__ nK,
               const float* __restrict__ nV, const float* __restrict__ initK,
               const float* __restrict__ initV, ushort* __restrict__ Yout)
{
  __shared__ ushort Kw[4][4096];   // [e][u*64+d] bf16, byte-addr ^ ((u&7)<<4)
  __shared__ ushort Vt[4][4096];   // [e][d*64+u] bf16, byte-addr ^ ((d&7)<<4)
  __shared__ ushort Pl[4][4096];   // per-wave P [m*64+u],  ^ ((m&7)<<4)

  const int blk = blockIdx.x;
  const int n = blk >> 7, c = blk & 127;
  const int t0 = c * 32;
  const int tid = threadIdx.x;
  const int lane = tid & 63;
  const int w = tid >> 6;
  const int l15 = lane & 15, lg = lane >> 4;

  // ---- Q A-fragments (global fp32 -> bf16, 1/8 score scale folded: exact pow2) ----
  short8 qf[4][2];
#pragma unroll
  for (int mi = 0; mi < 4; mi++) {
    int m = w * 64 + mi * 16 + l15;
    int t = t0 + (m & 31), h = m >> 5;
    const float* src = &Qp[((size_t)(n * 4096 + t)) * 512 + h * 64];
#pragma unroll
    for (int kk = 0; kk < 2; kk++) {
      int k = kk * 32 + lg * 8;
      f4 a = *(const f4*)&src[k];
      f4 b = *(const f4*)&src[k + 4];
      short8 v;
      v[0] = (short)f2bf(a.x * 0.125f); v[1] = (short)f2bf(a.y * 0.125f);
      v[2] = (short)f2bf(a.z * 0.125f); v[3] = (short)f2bf(a.w * 0.125f);
      v[4] = (short)f2bf(b.x * 0.125f); v[5] = (short)f2bf(b.y * 0.125f);
      v[6] = (short)f2bf(b.z * 0.125f); v[7] = (short)f2bf(b.w * 0.125f);
      qf[mi][kk] = v;
    }
  }

  // ---- stage K/V window: 4e x 64u x 64d, bf16, swizzled; u==63 zeroed ----
#pragma unroll 4
  for (int it = 0; it < 16; it++) {
    int idx = it * 256 + tid;
    int e = idx >> 10, u = (idx >> 4) & 63, d = (idx & 15) * 4;
    int s = t0 - 31 + u;
    int scl = s < 4095 ? s : 4095;      // clamp (u==63 data discarded anyway)
    const float* pK = (s >= 0) ? &nK[(((size_t)(n * 4 + e)) * 4096 + scl) * 64 + d]
                               : &initK[((size_t)e * 32 + (s + 32)) * 64 + d];
    const float* pV = (s >= 0) ? &nV[(((size_t)(n * 4 + e)) * 4096 + scl) * 64 + d]
                               : &initV[((size_t)e * 32 + (s + 32)) * 64 + d];
    f4 kv = *(const f4*)pK;
    f4 vv = *(const f4*)pV;
    if (u == 63) { kv = make_float4(0.f,0.f,0.f,0.f); vv = make_float4(0.f,0.f,0.f,0.f); }
    uint2 kp; kp.x = pk2(kv.x, kv.y); kp.y = pk2(kv.z, kv.w);
    int ka = (u * 128 + d * 2) ^ ((u & 7) << 4);
    *(uint2*)((char*)&Kw[e][0] + ka) = kp;
    ushort vb[4] = { f2bf(vv.x), f2bf(vv.y), f2bf(vv.z), f2bf(vv.w) };
#pragma unroll
    for (int q = 0; q < 4; q++) {
      int dq = d + q;
      int va = (dq * 128 + u * 2) ^ ((dq & 7) << 4);
      *(ushort*)((char*)&Vt[e][0] + va) = vb[q];
    }
  }
  __syncthreads();

  floatx4 Yacc[4][4];
#pragma unroll
  for (int mi = 0; mi < 4; mi++)
#pragma unroll
    for (int nd = 0; nd < 4; nd++) Yacc[mi][nd] = (floatx4){0.f,0.f,0.f,0.f};
  float mrun[4][4], lrun[4][4];
#pragma unroll
  for (int mi = 0; mi < 4; mi++)
#pragma unroll
    for (int r = 0; r < 4; r++) { mrun[mi][r] = -1e30f; lrun[mi][r] = 0.f; }

  const floatx4 zf = (floatx4){0.f,0.f,0.f,0.f};
  char* pb = (char*)&Pl[w][0];

#pragma unroll
  for (int half = 0; half < 2; half++) {
    floatx4 S[2][4][4];
    // ---- QK^T for 2 experts ----
#pragma unroll
    for (int ep = 0; ep < 2; ep++) {
      const int e = half * 2 + ep;
#pragma unroll
      for (int ni = 0; ni < 4; ni++) {
        const int urow = ni * 16 + l15;
        const int sw = (urow & 7) << 4;
        short8 kf0 = *(const short8*)((const char*)&Kw[e][0] + ((urow * 128 + lg * 16) ^ sw));
        short8 kf1 = *(const short8*)((const char*)&Kw[e][0] + ((urow * 128 + 64 + lg * 16) ^ sw));
#pragma unroll
        for (int mi = 0; mi < 4; mi++) {
          floatx4 t_ = __builtin_amdgcn_mfma_f32_16x16x32_bf16(qf[mi][0], kf0, zf, 0, 0, 0);
          S[ep][mi][ni] = __builtin_amdgcn_mfma_f32_16x16x32_bf16(qf[mi][1], kf1, t_, 0, 0, 0);
        }
      }
    }
    // ---- mask + online softmax (rows: (mi,r); cols: lanes l15 x ni x ep) ----
#pragma unroll
    for (int mi = 0; mi < 4; mi++)
#pragma unroll
      for (int r = 0; r < 4; r++) {
        const int iq = (mi & 1) * 16 + lg * 4 + r;
        float mx = mrun[mi][r];
#pragma unroll
        for (int ep = 0; ep < 2; ep++)
#pragma unroll
          for (int ni = 0; ni < 4; ni++) {
            const int u = ni * 16 + l15;
            float v = ((unsigned)(u - iq) < 32u) ? S[ep][mi][ni][r] : -1e30f;
            S[ep][mi][ni][r] = v;
            mx = fmaxf(mx, v);
          }
        mx = fmaxf(mx, __shfl_xor(mx, 1));
        mx = fmaxf(mx, __shfl_xor(mx, 2));
        mx = fmaxf(mx, __shfl_xor(mx, 4));
        mx = fmaxf(mx, __shfl_xor(mx, 8));
        float sc = __expf(mrun[mi][r] - mx);
        mrun[mi][r] = mx;
        float sum = 0.f;
#pragma unroll
        for (int ep = 0; ep < 2; ep++)
#pragma unroll
          for (int ni = 0; ni < 4; ni++) {
            float p = __expf(S[ep][mi][ni][r] - mx);
            S[ep][mi][ni][r] = p;
            sum += p;
          }
        sum += __shfl_xor(sum, 1);
        sum += __shfl_xor(sum, 2);
        sum += __shfl_xor(sum, 4);
        sum += __shfl_xor(sum, 8);
        lrun[mi][r] = lrun[mi][r] * sc + sum;
#pragma unroll
        for (int nd = 0; nd < 4; nd++) Yacc[mi][nd][r] *= sc;
      }
    // ---- per expert: P -> LDS (C-layout scatter), then PV MFMA ----
#pragma unroll
    for (int ep = 0; ep < 2; ep++) {
      const int e = half * 2 + ep;
#pragma unroll
      for (int mi = 0; mi < 4; mi++)
#pragma unroll
        for (int r = 0; r < 4; r++) {
          const int m = mi * 16 + lg * 4 + r;
          const int base = m * 128, sw = (m & 7) << 4;
#pragma unroll
          for (int ni = 0; ni < 4; ni++) {
            const int u = ni * 16 + l15;
            *(ushort*)(pb + ((base + u * 2) ^ sw)) = f2bf(S[ep][mi][ni][r]);
          }
        }
      asm volatile("s_waitcnt lgkmcnt(0)" ::: "memory");
      __builtin_amdgcn_sched_barrier(0);
#pragma unroll
      for (int kk = 0; kk < 2; kk++) {
        short8 pa[4];
#pragma unroll
        for (int mi = 0; mi < 4; mi++) {
          const int m = mi * 16 + l15;
          pa[mi] = *(const short8*)(pb + ((m * 128 + kk * 64 + lg * 16) ^ ((m & 7) << 4)));
        }
#pragma unroll
        for (int nd = 0; nd < 4; nd++) {
          const int dr = nd * 16 + l15;
          short8 vf = *(const short8*)((const char*)&Vt[e][0] +
                        ((dr * 128 + kk * 64 + lg * 16) ^ ((dr & 7) << 4)));
#pragma unroll
          for (int mi = 0; mi < 4; mi++)
            Yacc[mi][nd] = __builtin_amdgcn_mfma_f32_16x16x32_bf16(pa[mi], vf, Yacc[mi][nd], 0, 0, 0);
        }
      }
    }
  }

  // ---- normalize + store bf16 Y ----
#pragma unroll
  for (int mi = 0; mi < 4; mi++)
#pragma unroll
    for (int r = 0; r < 4; r++) {
      const float inv = 1.f / lrun[mi][r];
      const int m = w * 64 + mi * 16 + lg * 4 + r;
      const int t = t0 + (m & 31), h = m >> 5;
      ushort* dst = &Yout[((size_t)(n * 4096 + t)) * 512 + h * 64];
#pragma unroll
      for (int nd = 0; nd < 4; nd++)
        dst[nd * 16 + l15] = f2bf(Yacc[mi][nd][r] * inv);
    }
}

extern "C" void kernel_launch(void* const* d_in, const int* in_sizes, int n_in,
                              void* d_out, int out_size, void* d_ws, size_t ws_size,
                              hipStream_t stream) {
  const float* X     = (const float*)d_in[0];
  const float* wG    = (const float*)d_in[1];
  const float* bG    = (const float*)d_in[2];
  const float* wK    = (const float*)d_in[3];
  const float* wV    = (const float*)d_in[4];
  const float* wQ    = (const float*)d_in[5];
  const float* wO    = (const float*)d_in[6];
  const float* initK = (const float*)d_in[7];
  const float* initV = (const float*)d_in[8];
  float* out = (float*)d_out;

  float* ws = (float*)d_ws;
  ushort* Xbf  = (ushort*)(ws + 0);
  float*  gK   = ws + 0;
  float*  gV   = ws + 2097152;
  ushort* wAll = (ushort*)(ws + 4194304);
  ushort* wObf = (ushort*)(ws + 5046272);
  float*  Glin = ws + 5308416;
  float*  Kp   = ws + 5570560;
  ushort* Ybf  = (ushort*)Kp;
  float*  Vp   = ws + 9764864;
  float*  Qp   = ws + 13959168;
  float*  Aarr = ws + 18153472;

  conv_f32_bf16<<<2048, 256, 0, stream>>>(X, Xbf, 2097152);
  conv_weights<<<1664, 256, 0, stream>>>(wK, wV, wQ, wG, wAll);
  transpose_wO<<<2048, 256, 0, stream>>>(wO, wObf);
  proj_gemm_mfma<<<dim3(13, 64), 256, 0, stream>>>(Xbf, wAll, Kp, Vp, Qp, Glin);
  gate_kernel<<<2048, 256, 0, stream>>>(Glin, bG, Kp, Vp, gK, gV, Aarr);
  scan_kernel<<<512, 64, 0, stream>>>(gK, gV, Aarr, initK, initV);
  attn_mfma<<<256, 256, 0, stream>>>(Qp, gK, gV, initK, initV, Ybf);
  out_gemm_mfma<<<dim3(8, 64), 256, 0, stream>>>(Ybf, wObf, out);
}

// Round 5
// 222.911 us; speedup vs baseline: 3.1574x; 1.0163x over previous
//
#include <hip/hip_runtime.h>
#include <hip/hip_bf16.h>

// Caterpillar: N=2 T=4096 D=1024 H=8 E=4 L=32 DK=DV=64
// R5: proj GEMM -> 256x256 tile, 8 waves, ring-4 LDS buffers (BK=32),
//     counted vmcnt(4) + raw s_barrier per K-tile (T3+T4), setprio (T5),
//     XCD-chunked block swizzle (T1). Q written as pre-scaled bf16.
//     gate/scan/attn/out_gemm unchanged from passing R4.

using f4 = float4;
typedef __attribute__((ext_vector_type(8))) short short8;   // 8 bf16
typedef __attribute__((ext_vector_type(4))) float floatx4;  // 4 fp32 acc

__device__ __forceinline__ ushort f2bf(float x) {
  unsigned u = __float_as_uint(x);
  u += 0x7fffu + ((u >> 16) & 1u);   // RNE
  return (ushort)(u >> 16);
}
__device__ __forceinline__ unsigned pk2(float lo, float hi) {
  return (unsigned)f2bf(lo) | ((unsigned)f2bf(hi) << 16);
}

__device__ __forceinline__ void gll16(const void* g, void* l) {
  __builtin_amdgcn_global_load_lds((const __attribute__((address_space(1))) void*)g,
                                   (__attribute__((address_space(3))) void*)l, 16, 0, 0);
}

// ---------------- conversions ----------------
__global__ __launch_bounds__(256)
void conv_f32_bf16(const float* __restrict__ src, ushort* __restrict__ dst, int n4) {
  for (int i = blockIdx.x * blockDim.x + threadIdx.x; i < n4; i += gridDim.x * blockDim.x) {
    f4 v = ((const f4*)src)[i];
    ushort4 o; o.x = f2bf(v.x); o.y = f2bf(v.y); o.z = f2bf(v.z); o.w = f2bf(v.w);
    ((ushort4*)dst)[i] = o;
  }
}

// wAll rows: [0,512)=wK, [512,1024)=wV, [1024,1536)=wQ, [1536,1568)=wG, [1568,1792)=0
__global__ __launch_bounds__(256)
void conv_weights(const float* __restrict__ wK, const float* __restrict__ wV,
                  const float* __restrict__ wQ, const float* __restrict__ wG,
                  ushort* __restrict__ wAll) {
  int i4 = blockIdx.x * 256 + threadIdx.x;     // 0..458751
  int idx = i4 * 4;
  int row = idx >> 10;
  f4 v = make_float4(0.f, 0.f, 0.f, 0.f);
  if (row < 512)       v = *(const f4*)&wK[idx];
  else if (row < 1024) v = *(const f4*)&wV[idx - 524288];
  else if (row < 1536) v = *(const f4*)&wQ[idx - 1048576];
  else if (row < 1568) v = *(const f4*)&wG[idx - 1572864];
  ushort4 o; o.x = f2bf(v.x); o.y = f2bf(v.y); o.z = f2bf(v.z); o.w = f2bf(v.w);
  *(ushort4*)&wAll[idx] = o;
}

__global__ __launch_bounds__(256)
void transpose_wO(const float* __restrict__ wO, ushort* __restrict__ wObf) {
  int i = blockIdx.x * 256 + threadIdx.x;
  int n = i >> 9, k = i & 511;
  wObf[i] = f2bf(wO[(size_t)k * 1024 + n]);
}

// ---------------- projection GEMM: 256^2 tile, ring-4 BK=32, counted vmcnt ----------------
// C[m, f] = sum_k Xbf[m,k]*wAll[f,k]; grid 224 = 7 col-tiles x 32 row-tiles.
// ct 0,1 -> Kp ; 2,3 -> Vp ; 4,5 -> Qbf (x0.125, bf16) ; 6 -> Glin (cols<32).
#define PROJ_STEP(KT, WAITS, STAGE_) do {                                        \
  asm volatile("s_waitcnt vmcnt(" WAITS ")" ::: "memory");                       \
  __builtin_amdgcn_s_barrier();                                                  \
  asm volatile("" ::: "memory");                                                 \
  if (STAGE_) {                                                                  \
    const int k2 = ((KT) + 2) * 32;                                              \
    ushort* la = &As[(((KT) + 2) & 3) * 8192 + tid * 8];                         \
    ushort* lb = &Bs[(((KT) + 2) & 3) * 8192 + tid * 8];                         \
    gll16(gA + k2, la); gll16(gA + 131072 + k2, la + 4096);                      \
    gll16(gB + k2, lb); gll16(gB + 131072 + k2, lb + 4096);                      \
  }                                                                              \
  {                                                                              \
    const int ko = ((KT) & 3) * 8192;                                            \
    short8 bfrag[4];                                                             \
    _Pragma("unroll")                                                            \
    for (int ni = 0; ni < 4; ni++)                                               \
      bfrag[ni] = *(const short8*)(Bf + ko + ni * 512);                          \
    __builtin_amdgcn_s_setprio(1);                                               \
    _Pragma("unroll")                                                            \
    for (int mi = 0; mi < 8; mi++) {                                             \
      short8 afrag = *(const short8*)(Af + ko + mi * 512);                       \
      _Pragma("unroll")                                                          \
      for (int ni = 0; ni < 4; ni++)                                             \
        acc[mi][ni] = __builtin_amdgcn_mfma_f32_16x16x32_bf16(                   \
            afrag, bfrag[ni], acc[mi][ni], 0, 0, 0);                             \
    }                                                                            \
    __builtin_amdgcn_s_setprio(0);                                               \
  }                                                                              \
} while (0)

__global__ __launch_bounds__(512, 2)
void proj_gemm_256(const ushort* __restrict__ Xbf, const ushort* __restrict__ wAll,
                   float* __restrict__ Kp, float* __restrict__ Vp,
                   ushort* __restrict__ Qbf, float* __restrict__ Glin)
{
  __shared__ ushort As[4 * 8192];   // ring of 4: 256 rows x 32 k (bf16), 16KB each
  __shared__ ushort Bs[4 * 8192];

  const int tid = threadIdx.x;
  const int bid = blockIdx.x;               // 0..223, XCD-chunked
  const int xcd = bid & 7, slot = bid >> 3; // slot 0..27
  const int ct = slot % 7;
  const int my = xcd * 4 + slot / 7;        // 0..31
  const int m0 = my * 256;
  const int n0 = ct * 256;

  const int lane = tid & 63;
  const int w = tid >> 6;            // 0..7 (2 M x 4 N)
  const int wm = (w >> 2) * 128;
  const int wn = (w & 3) * 64;
  const int l15 = lane & 15, lg = lane >> 4;

  // staging: thread covers (row = tid>>2 [+128], chunk = tid&3) of the 256x32 tile
  const int srow = tid >> 2, sc8 = (tid & 3) * 8;
  const ushort* gA = Xbf  + (size_t)(m0 + srow) * 1024 + sc8;
  const ushort* gB = wAll + (size_t)(n0 + srow) * 1024 + sc8;

  // fragment bases
  const ushort* Af = As + (wm + l15) * 32 + lg * 8;
  const ushort* Bf = Bs + (wn + l15) * 32 + lg * 8;

  floatx4 acc[8][4];
#pragma unroll
  for (int mi = 0; mi < 8; mi++)
#pragma unroll
    for (int ni = 0; ni < 4; ni++) acc[mi][ni] = (floatx4){0.f, 0.f, 0.f, 0.f};

  // prologue: stage tiles 0 and 1
#pragma unroll
  for (int t_ = 0; t_ < 2; t_++) {
    const int k0 = t_ * 32;
    ushort* la = &As[t_ * 8192 + tid * 8];
    ushort* lb = &Bs[t_ * 8192 + tid * 8];
    gll16(gA + k0, la); gll16(gA + 131072 + k0, la + 4096);
    gll16(gB + k0, lb); gll16(gB + 131072 + k0, lb + 4096);
  }

#pragma unroll 1
  for (int kt = 0; kt < 30; ++kt) PROJ_STEP(kt, "4", true);
  PROJ_STEP(30, "4", false);
  PROJ_STEP(31, "0", false);

  // epilogue
#pragma unroll
  for (int mi = 0; mi < 8; mi++) {
    const int rm = m0 + wm + mi * 16 + lg * 4;
#pragma unroll
    for (int ni = 0; ni < 4; ni++) {
      const int cn = wn + ni * 16 + l15;   // 0..255 within col-tile
#pragma unroll
      for (int j = 0; j < 4; j++) {
        const float v = acc[mi][ni][j];
        if (ct < 2)      Kp [(size_t)(rm + j) * 512 + ct * 256 + cn] = v;
        else if (ct < 4) Vp [(size_t)(rm + j) * 512 + (ct - 2) * 256 + cn] = v;
        else if (ct < 6) Qbf[(size_t)(rm + j) * 512 + (ct - 4) * 256 + cn] = f2bf(v * 0.125f);
        else if (cn < 32) Glin[(size_t)(rm + j) * 32 + cn] = v;
      }
    }
  }
}

// ---------------- output GEMM (bf16 MFMA, R4 structure) ----------------
__global__ __launch_bounds__(256)
void out_gemm_mfma(const ushort* __restrict__ Ybf, const ushort* __restrict__ wObf,
                   float* __restrict__ out)
{
  __shared__ ushort As[4096];
  __shared__ ushort Bs[4096];
  const int tid = threadIdx.x;
  const int m0 = blockIdx.y * 128;
  const int n0 = blockIdx.x * 128;
  const int lane = tid & 63;
  const int wv = tid >> 6;
  const int wm = (wv >> 1) * 64, wn = (wv & 1) * 64;

  const int srow = tid >> 2, scol = (tid & 3) * 8;
  const ushort* gA = Ybf  + (size_t)(m0 + srow) * 512 + scol;
  const ushort* gB = wObf + (size_t)(n0 + srow) * 512 + scol;
  ushort* lA0 = &As[tid * 8]; ushort* lA1 = &As[2048 + tid * 8];
  ushort* lB0 = &Bs[tid * 8]; ushort* lB1 = &Bs[2048 + tid * 8];

  floatx4 acc[4][4];
#pragma unroll
  for (int i = 0; i < 4; i++)
#pragma unroll
    for (int j = 0; j < 4; j++) acc[i][j] = (floatx4){0.f, 0.f, 0.f, 0.f};

  const int fr = lane & 15;
  const int fk = (lane >> 4) * 8;
  const short8* pA[4]; const short8* pB[4];
#pragma unroll
  for (int i = 0; i < 4; i++) {
    pA[i] = (const short8*)&As[(wm + i * 16 + fr) * 32 + fk];
    pB[i] = (const short8*)&Bs[(wn + i * 16 + fr) * 32 + fk];
  }

  for (int k0 = 0; k0 < 512; k0 += 32) {
    gll16(gA + k0, lA0);
    gll16(gA + 32768 + k0, lA1);
    gll16(gB + k0, lB0);
    gll16(gB + 32768 + k0, lB1);
    __syncthreads();
    short8 a[4], b[4];
#pragma unroll
    for (int i = 0; i < 4; i++) { a[i] = *pA[i]; b[i] = *pB[i]; }
#pragma unroll
    for (int mi = 0; mi < 4; mi++)
#pragma unroll
      for (int ni = 0; ni < 4; ni++)
        acc[mi][ni] = __builtin_amdgcn_mfma_f32_16x16x32_bf16(a[mi], b[ni], acc[mi][ni], 0, 0, 0);
    __syncthreads();
  }

  const int fq = lane >> 4;
#pragma unroll
  for (int mi = 0; mi < 4; mi++) {
    int rm = m0 + wm + mi * 16 + fq * 4;
#pragma unroll
    for (int ni = 0; ni < 4; ni++) {
      int cn = n0 + wn + ni * 16 + fr;
#pragma unroll
      for (int j = 0; j < 4; j++)
        out[(size_t)(rm + j) * 1024 + cn] = acc[mi][ni][j];
    }
  }
}

// ---------------- gate/mix ----------------
__global__ __launch_bounds__(256)
void gate_kernel(const float* __restrict__ Glin, const float* __restrict__ bG,
                 const float* __restrict__ Kp, const float* __restrict__ Vp,
                 float* __restrict__ gK, float* __restrict__ gV, float* __restrict__ Aout)
{
  const int nt = blockIdx.x * 4 + (threadIdx.x >> 6);
  const int lane = threadIdx.x & 63;
  const int n = nt >> 12;
  const int t = nt & 4095;

  float g[32];
  float gsum[4] = {0.f, 0.f, 0.f, 0.f};
#pragma unroll
  for (int f = 0; f < 32; f++) {
    float z = Glin[(size_t)nt * 32 + f] + bG[f];
    float s = 1.f / (1.f + __expf(-z));
    g[f] = s;
    gsum[f & 3] += s;
  }
  if (lane < 4) {
    float a = 1.f - fminf(gsum[lane], 1.f);
    Aout[(size_t)(n * 4 + lane) * 4096 + t] = a;
  }
  float gk[4] = {0.f, 0.f, 0.f, 0.f}, gv[4] = {0.f, 0.f, 0.f, 0.f};
#pragma unroll
  for (int h = 0; h < 8; h++) {
    float kv = Kp[(size_t)nt * 512 + h * 64 + lane];
    float vv = Vp[(size_t)nt * 512 + h * 64 + lane];
#pragma unroll
    for (int e = 0; e < 4; e++) {
      gk[e] = fmaf(g[h * 4 + e], kv, gk[e]);
      gv[e] = fmaf(g[h * 4 + e], vv, gv[e]);
    }
  }
#pragma unroll
  for (int e = 0; e < 4; e++) {
    size_t base = ((size_t)(n * 4 + e) * 4096 + t) * 64 + lane;
    gK[base] = gk[e];
    gV[base] = gv[e];
  }
}

// ---------------- chunked scan ----------------
__global__ __launch_bounds__(64)
void scan_kernel(float* __restrict__ gK, float* __restrict__ gV,
                 const float* __restrict__ Aarr,
                 const float* __restrict__ initK, const float* __restrict__ initV)
{
  __shared__ float sB[128 * 64];
  __shared__ float sA[128];
  const int b = blockIdx.x;
  const int half = b >> 8, sub = b & 255;
  float* gX = half ? gV : gK;
  const float* initX = half ? initV : initK;
  const int n = sub >> 7, r = sub & 127, e = r >> 5, l = r & 31;
  const int tbase = l * 128;
  const size_t base = ((size_t)(n * 4 + e) * 4096 + tbase) * 64;
  const int tid = threadIdx.x;

  const f4* src = (const f4*)&gX[base];
#pragma unroll
  for (int q = 0; q < 32; q++)
    *(f4*)&sB[(tid + q * 64) * 4] = src[tid + q * 64];
  sA[tid]      = Aarr[(size_t)(n * 4 + e) * 4096 + tbase + tid];
  sA[64 + tid] = Aarr[(size_t)(n * 4 + e) * 4096 + tbase + 64 + tid];
  __syncthreads();

  float state = initX[((size_t)e * 32 + l) * 64 + tid];
  float* dst = &gX[base];
  for (int c = 0; c < 128; c++) {
    state = fmaf(sA[c], state, sB[c * 64 + tid]);
    dst[c * 64 + tid] = state;
  }
}

// ---------------- MFMA window attention (Q pre-scaled bf16) ----------------
__global__ __launch_bounds__(256, 1)
void attn_mfma(const ushort* __restrict__ Qbf, const float* __restrict__ nK,
               const float* __restrict__ nV, const float* __restrict__ initK,
               const float* __restrict__ initV, ushort* __restrict__ Yout)
{
  __shared__ ushort Kw[4][4096];   // [e][u*64+d] bf16, byte-addr ^ ((u&7)<<4)
  __shared__ ushort Vt[4][4096];   // [e][d*64+u] bf16, byte-addr ^ ((d&7)<<4)
  __shared__ ushort Pl[4][4096];   // per-wave P [m*64+u],  ^ ((m&7)<<4)

  const int blk = blockIdx.x;
  const int n = blk >> 7, c = blk & 127;
  const int t0 = c * 32;
  const int tid = threadIdx.x;
  const int lane = tid & 63;
  const int w = tid >> 6;
  const int l15 = lane & 15, lg = lane >> 4;

  // ---- Q A-fragments: direct bf16 loads (pre-scaled in proj epilogue) ----
  short8 qf[4][2];
#pragma unroll
  for (int mi = 0; mi < 4; mi++) {
    int m = w * 64 + mi * 16 + l15;
    int t = t0 + (m & 31), h = m >> 5;
    const ushort* src = &Qbf[((size_t)(n * 4096 + t)) * 512 + h * 64];
#pragma unroll
    for (int kk = 0; kk < 2; kk++)
      qf[mi][kk] = *(const short8*)&src[kk * 32 + lg * 8];
  }

  // ---- stage K/V window: 4e x 64u x 64d, bf16, swizzled; u==63 zeroed ----
#pragma unroll 4
  for (int it = 0; it < 16; it++) {
    int idx = it * 256 + tid;
    int e = idx >> 10, u = (idx >> 4) & 63, d = (idx & 15) * 4;
    int s = t0 - 31 + u;
    int scl = s < 4095 ? s : 4095;
    const float* pK = (s >= 0) ? &nK[(((size_t)(n * 4 + e)) * 4096 + scl) * 64 + d]
                               : &initK[((size_t)e * 32 + (s + 32)) * 64 + d];
    const float* pV = (s >= 0) ? &nV[(((size_t)(n * 4 + e)) * 4096 + scl) * 64 + d]
                               : &initV[((size_t)e * 32 + (s + 32)) * 64 + d];
    f4 kv = *(const f4*)pK;
    f4 vv = *(const f4*)pV;
    if (u == 63) { kv = make_float4(0.f,0.f,0.f,0.f); vv = make_float4(0.f,0.f,0.f,0.f); }
    uint2 kp; kp.x = pk2(kv.x, kv.y); kp.y = pk2(kv.z, kv.w);
    int ka = (u * 128 + d * 2) ^ ((u & 7) << 4);
    *(uint2*)((char*)&Kw[e][0] + ka) = kp;
    ushort vb[4] = { f2bf(vv.x), f2bf(vv.y), f2bf(vv.z), f2bf(vv.w) };
#pragma unroll
    for (int q = 0; q < 4; q++) {
      int dq = d + q;
      int va = (dq * 128 + u * 2) ^ ((dq & 7) << 4);
      *(ushort*)((char*)&Vt[e][0] + va) = vb[q];
    }
  }
  __syncthreads();

  floatx4 Yacc[4][4];
#pragma unroll
  for (int mi = 0; mi < 4; mi++)
#pragma unroll
    for (int nd = 0; nd < 4; nd++) Yacc[mi][nd] = (floatx4){0.f,0.f,0.f,0.f};
  float mrun[4][4], lrun[4][4];
#pragma unroll
  for (int mi = 0; mi < 4; mi++)
#pragma unroll
    for (int r = 0; r < 4; r++) { mrun[mi][r] = -1e30f; lrun[mi][r] = 0.f; }

  const floatx4 zf = (floatx4){0.f,0.f,0.f,0.f};
  char* pb = (char*)&Pl[w][0];

#pragma unroll
  for (int half = 0; half < 2; half++) {
    floatx4 S[2][4][4];
#pragma unroll
    for (int ep = 0; ep < 2; ep++) {
      const int e = half * 2 + ep;
#pragma unroll
      for (int ni = 0; ni < 4; ni++) {
        const int urow = ni * 16 + l15;
        const int sw = (urow & 7) << 4;
        short8 kf0 = *(const short8*)((const char*)&Kw[e][0] + ((urow * 128 + lg * 16) ^ sw));
        short8 kf1 = *(const short8*)((const char*)&Kw[e][0] + ((urow * 128 + 64 + lg * 16) ^ sw));
#pragma unroll
        for (int mi = 0; mi < 4; mi++) {
          floatx4 t_ = __builtin_amdgcn_mfma_f32_16x16x32_bf16(qf[mi][0], kf0, zf, 0, 0, 0);
          S[ep][mi][ni] = __builtin_amdgcn_mfma_f32_16x16x32_bf16(qf[mi][1], kf1, t_, 0, 0, 0);
        }
      }
    }
#pragma unroll
    for (int mi = 0; mi < 4; mi++)
#pragma unroll
      for (int r = 0; r < 4; r++) {
        const int iq = (mi & 1) * 16 + lg * 4 + r;
        float mx = mrun[mi][r];
#pragma unroll
        for (int ep = 0; ep < 2; ep++)
#pragma unroll
          for (int ni = 0; ni < 4; ni++) {
            const int u = ni * 16 + l15;
            float v = ((unsigned)(u - iq) < 32u) ? S[ep][mi][ni][r] : -1e30f;
            S[ep][mi][ni][r] = v;
            mx = fmaxf(mx, v);
          }
        mx = fmaxf(mx, __shfl_xor(mx, 1));
        mx = fmaxf(mx, __shfl_xor(mx, 2));
        mx = fmaxf(mx, __shfl_xor(mx, 4));
        mx = fmaxf(mx, __shfl_xor(mx, 8));
        float sc = __expf(mrun[mi][r] - mx);
        mrun[mi][r] = mx;
        float sum = 0.f;
#pragma unroll
        for (int ep = 0; ep < 2; ep++)
#pragma unroll
          for (int ni = 0; ni < 4; ni++) {
            float p = __expf(S[ep][mi][ni][r] - mx);
            S[ep][mi][ni][r] = p;
            sum += p;
          }
        sum += __shfl_xor(sum, 1);
        sum += __shfl_xor(sum, 2);
        sum += __shfl_xor(sum, 4);
        sum += __shfl_xor(sum, 8);
        lrun[mi][r] = lrun[mi][r] * sc + sum;
#pragma unroll
        for (int nd = 0; nd < 4; nd++) Yacc[mi][nd][r] *= sc;
      }
#pragma unroll
    for (int ep = 0; ep < 2; ep++) {
      const int e = half * 2 + ep;
#pragma unroll
      for (int mi = 0; mi < 4; mi++)
#pragma unroll
        for (int r = 0; r < 4; r++) {
          const int m = mi * 16 + lg * 4 + r;
          const int base = m * 128, sw = (m & 7) << 4;
#pragma unroll
          for (int ni = 0; ni < 4; ni++) {
            const int u = ni * 16 + l15;
            *(ushort*)(pb + ((base + u * 2) ^ sw)) = f2bf(S[ep][mi][ni][r]);
          }
        }
      asm volatile("s_waitcnt lgkmcnt(0)" ::: "memory");
      __builtin_amdgcn_sched_barrier(0);
#pragma unroll
      for (int kk = 0; kk < 2; kk++) {
        short8 pa[4];
#pragma unroll
        for (int mi = 0; mi < 4; mi++) {
          const int m = mi * 16 + l15;
          pa[mi] = *(const short8*)(pb + ((m * 128 + kk * 64 + lg * 16) ^ ((m & 7) << 4)));
        }
#pragma unroll
        for (int nd = 0; nd < 4; nd++) {
          const int dr = nd * 16 + l15;
          short8 vf = *(const short8*)((const char*)&Vt[e][0] +
                        ((dr * 128 + kk * 64 + lg * 16) ^ ((dr & 7) << 4)));
#pragma unroll
          for (int mi = 0; mi < 4; mi++)
            Yacc[mi][nd] = __builtin_amdgcn_mfma_f32_16x16x32_bf16(pa[mi], vf, Yacc[mi][nd], 0, 0, 0);
        }
      }
    }
  }

#pragma unroll
  for (int mi = 0; mi < 4; mi++)
#pragma unroll
    for (int r = 0; r < 4; r++) {
      const float inv = 1.f / lrun[mi][r];
      const int m = w * 64 + mi * 16 + lg * 4 + r;
      const int t = t0 + (m & 31), h = m >> 5;
      ushort* dst = &Yout[((size_t)(n * 4096 + t)) * 512 + h * 64];
#pragma unroll
      for (int nd = 0; nd < 4; nd++)
        dst[nd * 16 + l15] = f2bf(Yacc[mi][nd][r] * inv);
    }
}

extern "C" void kernel_launch(void* const* d_in, const int* in_sizes, int n_in,
                              void* d_out, int out_size, void* d_ws, size_t ws_size,
                              hipStream_t stream) {
  const float* X     = (const float*)d_in[0];
  const float* wG    = (const float*)d_in[1];
  const float* bG    = (const float*)d_in[2];
  const float* wK    = (const float*)d_in[3];
  const float* wV    = (const float*)d_in[4];
  const float* wQ    = (const float*)d_in[5];
  const float* wO    = (const float*)d_in[6];
  const float* initK = (const float*)d_in[7];
  const float* initV = (const float*)d_in[8];
  float* out = (float*)d_out;

  float* ws = (float*)d_ws;
  // region 0: Xbf (16MB) -> later gK(8MB)+gV(8MB)
  ushort* Xbf  = (ushort*)(ws + 0);
  float*  gK   = ws + 0;
  float*  gV   = ws + 2097152;
  ushort* wAll = (ushort*)(ws + 4194304);     // 1792x1024 bf16
  ushort* wObf = (ushort*)(ws + 5111808);     // 1024x512 bf16
  float*  Glin = ws + 5373952;                // 8192x32 f32
  float*  Kp   = ws + 5636096;                // 8192x512 f32 -> later Ybf (bf16)
  ushort* Ybf  = (ushort*)Kp;
  float*  Vp   = ws + 9830400;                // 8192x512 f32
  ushort* Qbf  = (ushort*)(ws + 14024704);    // 8192x512 bf16 (pre-scaled 1/8)
  float*  Aarr = ws + 16121856;               // 2*4*4096

  conv_f32_bf16<<<2048, 256, 0, stream>>>(X, Xbf, 2097152);
  conv_weights<<<1792, 256, 0, stream>>>(wK, wV, wQ, wG, wAll);
  transpose_wO<<<2048, 256, 0, stream>>>(wO, wObf);
  proj_gemm_256<<<224, 512, 0, stream>>>(Xbf, wAll, Kp, Vp, Qbf, Glin);
  gate_kernel<<<2048, 256, 0, stream>>>(Glin, bG, Kp, Vp, gK, gV, Aarr);
  scan_kernel<<<512, 64, 0, stream>>>(gK, gV, Aarr, initK, initV);
  attn_mfma<<<256, 256, 0, stream>>>(Qbf, gK, gV, initK, initV, Ybf);
  out_gemm_mfma<<<dim3(8, 64), 256, 0, stream>>>(Ybf, wObf, out);
}

// Round 6
// 222.599 us; speedup vs baseline: 3.1618x; 1.0014x over previous
//
#include <hip/hip_runtime.h>
#include <hip/hip_bf16.h>

// Caterpillar: N=2 T=4096 D=1024 H=8 E=4 L=32 DK=DV=64
// R6: single-barrier ring-4 pipelined GEMMs (stage t+3, counted vmcnt, setprio):
//     proj (256x256, vmcnt 8/8/4/0) and out_gemm (256x128, vmcnt 6/6/3/0).
//     gate/scan/attn unchanged from passing R5.

using f4 = float4;
typedef __attribute__((ext_vector_type(8))) short short8;   // 8 bf16
typedef __attribute__((ext_vector_type(4))) float floatx4;  // 4 fp32 acc

__device__ __forceinline__ ushort f2bf(float x) {
  unsigned u = __float_as_uint(x);
  u += 0x7fffu + ((u >> 16) & 1u);   // RNE
  return (ushort)(u >> 16);
}
__device__ __forceinline__ unsigned pk2(float lo, float hi) {
  return (unsigned)f2bf(lo) | ((unsigned)f2bf(hi) << 16);
}

__device__ __forceinline__ void gll16(const void* g, void* l) {
  __builtin_amdgcn_global_load_lds((const __attribute__((address_space(1))) void*)g,
                                   (__attribute__((address_space(3))) void*)l, 16, 0, 0);
}

// ---------------- conversions ----------------
__global__ __launch_bounds__(256)
void conv_f32_bf16(const float* __restrict__ src, ushort* __restrict__ dst, int n4) {
  for (int i = blockIdx.x * blockDim.x + threadIdx.x; i < n4; i += gridDim.x * blockDim.x) {
    f4 v = ((const f4*)src)[i];
    ushort4 o; o.x = f2bf(v.x); o.y = f2bf(v.y); o.z = f2bf(v.z); o.w = f2bf(v.w);
    ((ushort4*)dst)[i] = o;
  }
}

// wAll rows: [0,512)=wK, [512,1024)=wV, [1024,1536)=wQ, [1536,1568)=wG, [1568,1792)=0
__global__ __launch_bounds__(256)
void conv_weights(const float* __restrict__ wK, const float* __restrict__ wV,
                  const float* __restrict__ wQ, const float* __restrict__ wG,
                  ushort* __restrict__ wAll) {
  int i4 = blockIdx.x * 256 + threadIdx.x;     // 0..458751
  int idx = i4 * 4;
  int row = idx >> 10;
  f4 v = make_float4(0.f, 0.f, 0.f, 0.f);
  if (row < 512)       v = *(const f4*)&wK[idx];
  else if (row < 1024) v = *(const f4*)&wV[idx - 524288];
  else if (row < 1536) v = *(const f4*)&wQ[idx - 1048576];
  else if (row < 1568) v = *(const f4*)&wG[idx - 1572864];
  ushort4 o; o.x = f2bf(v.x); o.y = f2bf(v.y); o.z = f2bf(v.z); o.w = f2bf(v.w);
  *(ushort4*)&wAll[idx] = o;
}

__global__ __launch_bounds__(256)
void transpose_wO(const float* __restrict__ wO, ushort* __restrict__ wObf) {
  int i = blockIdx.x * 256 + threadIdx.x;
  int n = i >> 9, k = i & 511;
  wObf[i] = f2bf(wO[(size_t)k * 1024 + n]);
}

// ---------------- projection GEMM: 256^2 tile, ring-4 BK=32, stage t+3 ----------------
// One s_barrier + one counted vmcnt per K-tile. Slot (t+3)&3 == (t-1)&3 is dead
// (all waves consumed its reads into registers before the tile-t barrier).
#define PROJ_STEP(KT, WAITS, STAGE_) do {                                        \
  asm volatile("s_waitcnt vmcnt(" WAITS ")" ::: "memory");                       \
  __builtin_amdgcn_s_barrier();                                                  \
  if (STAGE_) {                                                                  \
    const int k3 = ((KT) + 3) * 32;                                              \
    ushort* la = &As[(((KT) + 3) & 3) * 8192 + tid * 8];                         \
    ushort* lb = &Bs[(((KT) + 3) & 3) * 8192 + tid * 8];                         \
    gll16(gA + k3, la); gll16(gA + 131072 + k3, la + 4096);                      \
    gll16(gB + k3, lb); gll16(gB + 131072 + k3, lb + 4096);                      \
  }                                                                              \
  {                                                                              \
    const int ko = ((KT) & 3) * 8192;                                            \
    short8 bfrag[4];                                                             \
    _Pragma("unroll")                                                            \
    for (int ni = 0; ni < 4; ni++)                                               \
      bfrag[ni] = *(const short8*)(Bf + ko + ni * 512);                          \
    __builtin_amdgcn_s_setprio(1);                                               \
    _Pragma("unroll")                                                            \
    for (int mi = 0; mi < 8; mi++) {                                             \
      short8 afrag = *(const short8*)(Af + ko + mi * 512);                       \
      _Pragma("unroll")                                                          \
      for (int ni = 0; ni < 4; ni++)                                             \
        acc[mi][ni] = __builtin_amdgcn_mfma_f32_16x16x32_bf16(                   \
            afrag, bfrag[ni], acc[mi][ni], 0, 0, 0);                             \
    }                                                                            \
    __builtin_amdgcn_s_setprio(0);                                               \
  }                                                                              \
} while (0)

__global__ __launch_bounds__(512, 2)
void proj_gemm_256(const ushort* __restrict__ Xbf, const ushort* __restrict__ wAll,
                   float* __restrict__ Kp, float* __restrict__ Vp,
                   ushort* __restrict__ Qbf, float* __restrict__ Glin)
{
  __shared__ ushort As[4 * 8192];   // ring of 4: 256 rows x 32 k (bf16), 16KB each
  __shared__ ushort Bs[4 * 8192];

  const int tid = threadIdx.x;
  const int bid = blockIdx.x;               // 0..223, XCD-chunked
  const int xcd = bid & 7, slot = bid >> 3; // slot 0..27
  const int ct = slot % 7;
  const int my = xcd * 4 + slot / 7;        // 0..31
  const int m0 = my * 256;
  const int n0 = ct * 256;

  const int lane = tid & 63;
  const int w = tid >> 6;            // 0..7 (2 M x 4 N)
  const int wm = (w >> 2) * 128;
  const int wn = (w & 3) * 64;
  const int l15 = lane & 15, lg = lane >> 4;

  const int srow = tid >> 2, sc8 = (tid & 3) * 8;
  const ushort* gA = Xbf  + (size_t)(m0 + srow) * 1024 + sc8;
  const ushort* gB = wAll + (size_t)(n0 + srow) * 1024 + sc8;

  const ushort* Af = As + (wm + l15) * 32 + lg * 8;
  const ushort* Bf = Bs + (wn + l15) * 32 + lg * 8;

  floatx4 acc[8][4];
#pragma unroll
  for (int mi = 0; mi < 8; mi++)
#pragma unroll
    for (int ni = 0; ni < 4; ni++) acc[mi][ni] = (floatx4){0.f, 0.f, 0.f, 0.f};

  // prologue: stage tiles 0,1,2 (12 loads outstanding)
#pragma unroll
  for (int t_ = 0; t_ < 3; t_++) {
    const int k0 = t_ * 32;
    ushort* la = &As[t_ * 8192 + tid * 8];
    ushort* lb = &Bs[t_ * 8192 + tid * 8];
    gll16(gA + k0, la); gll16(gA + 131072 + k0, la + 4096);
    gll16(gB + k0, lb); gll16(gB + 131072 + k0, lb + 4096);
  }

#pragma unroll 1
  for (int kt = 0; kt < 29; ++kt) PROJ_STEP(kt, "8", true);
  PROJ_STEP(29, "8", false);
  PROJ_STEP(30, "4", false);
  PROJ_STEP(31, "0", false);

  // epilogue
#pragma unroll
  for (int mi = 0; mi < 8; mi++) {
    const int rm = m0 + wm + mi * 16 + lg * 4;
#pragma unroll
    for (int ni = 0; ni < 4; ni++) {
      const int cn = wn + ni * 16 + l15;   // 0..255 within col-tile
#pragma unroll
      for (int j = 0; j < 4; j++) {
        const float v = acc[mi][ni][j];
        if (ct < 2)      Kp [(size_t)(rm + j) * 512 + ct * 256 + cn] = v;
        else if (ct < 4) Vp [(size_t)(rm + j) * 512 + (ct - 2) * 256 + cn] = v;
        else if (ct < 6) Qbf[(size_t)(rm + j) * 512 + (ct - 4) * 256 + cn] = f2bf(v * 0.125f);
        else if (cn < 32) Glin[(size_t)(rm + j) * 32 + cn] = v;
      }
    }
  }
}

// ---------------- output GEMM: 256x128 tile, ring-4 BK=32, stage t+3 ----------------
#define OUT_STEP(KT, WAITS, STAGE_) do {                                         \
  asm volatile("s_waitcnt vmcnt(" WAITS ")" ::: "memory");                       \
  __builtin_amdgcn_s_barrier();                                                  \
  if (STAGE_) {                                                                  \
    const int k3 = ((KT) + 3) * 32;                                              \
    ushort* la = &As[(((KT) + 3) & 3) * 8192 + tid * 8];                         \
    ushort* lb = &Bs[(((KT) + 3) & 3) * 4096 + tid * 8];                         \
    gll16(gA + k3, la); gll16(gA + 65536 + k3, la + 4096);                       \
    gll16(gB + k3, lb);                                                          \
  }                                                                              \
  {                                                                              \
    const int koA = ((KT) & 3) * 8192;                                           \
    const int koB = ((KT) & 3) * 4096;                                           \
    short8 bfrag[4];                                                             \
    _Pragma("unroll")                                                            \
    for (int ni = 0; ni < 4; ni++)                                               \
      bfrag[ni] = *(const short8*)(Bf + koB + ni * 512);                         \
    __builtin_amdgcn_s_setprio(1);                                               \
    _Pragma("unroll")                                                            \
    for (int mi = 0; mi < 4; mi++) {                                             \
      short8 afrag = *(const short8*)(Af + koA + mi * 512);                      \
      _Pragma("unroll")                                                          \
      for (int ni = 0; ni < 4; ni++)                                             \
        acc[mi][ni] = __builtin_amdgcn_mfma_f32_16x16x32_bf16(                   \
            afrag, bfrag[ni], acc[mi][ni], 0, 0, 0);                             \
    }                                                                            \
    __builtin_amdgcn_s_setprio(0);                                               \
  }                                                                              \
} while (0)

__global__ __launch_bounds__(512, 2)
void out_gemm_256(const ushort* __restrict__ Ybf, const ushort* __restrict__ wObf,
                  float* __restrict__ out)
{
  __shared__ ushort As[4 * 8192];   // 256 rows x 32 k per slot (16KB)
  __shared__ ushort Bs[4 * 4096];   // 128 rows x 32 k per slot (8KB)

  const int tid = threadIdx.x;
  const int bid = blockIdx.x;               // 0..255, XCD-chunked
  const int xcd = bid & 7, slot = bid >> 3; // 0..31
  const int ct = slot & 7;                  // 8 col-tiles of 128
  const int my = xcd * 4 + (slot >> 3);     // 0..31 row-tiles of 256
  const int m0 = my * 256;
  const int n0 = ct * 128;

  const int lane = tid & 63;
  const int w = tid >> 6;            // 8 waves: 4M x 2N, wave tile 64x64
  const int wm = (w >> 1) * 64;
  const int wn = (w & 1) * 64;
  const int l15 = lane & 15, lg = lane >> 4;

  const int srow = tid >> 2, sc8 = (tid & 3) * 8;
  const ushort* gA = Ybf  + (size_t)(m0 + srow) * 512 + sc8;
  const ushort* gB = wObf + (size_t)(n0 + srow) * 512 + sc8;

  const ushort* Af = As + (wm + l15) * 32 + lg * 8;
  const ushort* Bf = Bs + (wn + l15) * 32 + lg * 8;

  floatx4 acc[4][4];
#pragma unroll
  for (int mi = 0; mi < 4; mi++)
#pragma unroll
    for (int ni = 0; ni < 4; ni++) acc[mi][ni] = (floatx4){0.f, 0.f, 0.f, 0.f};

  // prologue: stage tiles 0,1,2 (9 loads outstanding)
#pragma unroll
  for (int t_ = 0; t_ < 3; t_++) {
    const int k0 = t_ * 32;
    ushort* la = &As[t_ * 8192 + tid * 8];
    ushort* lb = &Bs[t_ * 4096 + tid * 8];
    gll16(gA + k0, la); gll16(gA + 65536 + k0, la + 4096);
    gll16(gB + k0, lb);
  }

#pragma unroll 1
  for (int kt = 0; kt < 13; ++kt) OUT_STEP(kt, "6", true);
  OUT_STEP(13, "6", false);
  OUT_STEP(14, "3", false);
  OUT_STEP(15, "0", false);

#pragma unroll
  for (int mi = 0; mi < 4; mi++) {
    const int rm = m0 + wm + mi * 16 + lg * 4;
#pragma unroll
    for (int ni = 0; ni < 4; ni++) {
      const int cn = n0 + wn + ni * 16 + l15;
#pragma unroll
      for (int j = 0; j < 4; j++)
        out[(size_t)(rm + j) * 1024 + cn] = acc[mi][ni][j];
    }
  }
}

// ---------------- gate/mix ----------------
__global__ __launch_bounds__(256)
void gate_kernel(const float* __restrict__ Glin, const float* __restrict__ bG,
                 const float* __restrict__ Kp, const float* __restrict__ Vp,
                 float* __restrict__ gK, float* __restrict__ gV, float* __restrict__ Aout)
{
  const int nt = blockIdx.x * 4 + (threadIdx.x >> 6);
  const int lane = threadIdx.x & 63;
  const int n = nt >> 12;
  const int t = nt & 4095;

  float g[32];
  float gsum[4] = {0.f, 0.f, 0.f, 0.f};
#pragma unroll
  for (int f = 0; f < 32; f++) {
    float z = Glin[(size_t)nt * 32 + f] + bG[f];
    float s = 1.f / (1.f + __expf(-z));
    g[f] = s;
    gsum[f & 3] += s;
  }
  if (lane < 4) {
    float a = 1.f - fminf(gsum[lane], 1.f);
    Aout[(size_t)(n * 4 + lane) * 4096 + t] = a;
  }
  float gk[4] = {0.f, 0.f, 0.f, 0.f}, gv[4] = {0.f, 0.f, 0.f, 0.f};
#pragma unroll
  for (int h = 0; h < 8; h++) {
    float kv = Kp[(size_t)nt * 512 + h * 64 + lane];
    float vv = Vp[(size_t)nt * 512 + h * 64 + lane];
#pragma unroll
    for (int e = 0; e < 4; e++) {
      gk[e] = fmaf(g[h * 4 + e], kv, gk[e]);
      gv[e] = fmaf(g[h * 4 + e], vv, gv[e]);
    }
  }
#pragma unroll
  for (int e = 0; e < 4; e++) {
    size_t base = ((size_t)(n * 4 + e) * 4096 + t) * 64 + lane;
    gK[base] = gk[e];
    gV[base] = gv[e];
  }
}

// ---------------- chunked scan ----------------
__global__ __launch_bounds__(64)
void scan_kernel(float* __restrict__ gK, float* __restrict__ gV,
                 const float* __restrict__ Aarr,
                 const float* __restrict__ initK, const float* __restrict__ initV)
{
  __shared__ float sB[128 * 64];
  __shared__ float sA[128];
  const int b = blockIdx.x;
  const int half = b >> 8, sub = b & 255;
  float* gX = half ? gV : gK;
  const float* initX = half ? initV : initK;
  const int n = sub >> 7, r = sub & 127, e = r >> 5, l = r & 31;
  const int tbase = l * 128;
  const size_t base = ((size_t)(n * 4 + e) * 4096 + tbase) * 64;
  const int tid = threadIdx.x;

  const f4* src = (const f4*)&gX[base];
#pragma unroll
  for (int q = 0; q < 32; q++)
    *(f4*)&sB[(tid + q * 64) * 4] = src[tid + q * 64];
  sA[tid]      = Aarr[(size_t)(n * 4 + e) * 4096 + tbase + tid];
  sA[64 + tid] = Aarr[(size_t)(n * 4 + e) * 4096 + tbase + 64 + tid];
  __syncthreads();

  float state = initX[((size_t)e * 32 + l) * 64 + tid];
  float* dst = &gX[base];
  for (int c = 0; c < 128; c++) {
    state = fmaf(sA[c], state, sB[c * 64 + tid]);
    dst[c * 64 + tid] = state;
  }
}

// ---------------- MFMA window attention (Q pre-scaled bf16) ----------------
__global__ __launch_bounds__(256, 1)
void attn_mfma(const ushort* __restrict__ Qbf, const float* __restrict__ nK,
               const float* __restrict__ nV, const float* __restrict__ initK,
               const float* __restrict__ initV, ushort* __restrict__ Yout)
{
  __shared__ ushort Kw[4][4096];   // [e][u*64+d] bf16, byte-addr ^ ((u&7)<<4)
  __shared__ ushort Vt[4][4096];   // [e][d*64+u] bf16, byte-addr ^ ((d&7)<<4)
  __shared__ ushort Pl[4][4096];   // per-wave P [m*64+u],  ^ ((m&7)<<4)

  const int blk = blockIdx.x;
  const int n = blk >> 7, c = blk & 127;
  const int t0 = c * 32;
  const int tid = threadIdx.x;
  const int lane = tid & 63;
  const int w = tid >> 6;
  const int l15 = lane & 15, lg = lane >> 4;

  short8 qf[4][2];
#pragma unroll
  for (int mi = 0; mi < 4; mi++) {
    int m = w * 64 + mi * 16 + l15;
    int t = t0 + (m & 31), h = m >> 5;
    const ushort* src = &Qbf[((size_t)(n * 4096 + t)) * 512 + h * 64];
#pragma unroll
    for (int kk = 0; kk < 2; kk++)
      qf[mi][kk] = *(const short8*)&src[kk * 32 + lg * 8];
  }

#pragma unroll 4
  for (int it = 0; it < 16; it++) {
    int idx = it * 256 + tid;
    int e = idx >> 10, u = (idx >> 4) & 63, d = (idx & 15) * 4;
    int s = t0 - 31 + u;
    int scl = s < 4095 ? s : 4095;
    const float* pK = (s >= 0) ? &nK[(((size_t)(n * 4 + e)) * 4096 + scl) * 64 + d]
                               : &initK[((size_t)e * 32 + (s + 32)) * 64 + d];
    const float* pV = (s >= 0) ? &nV[(((size_t)(n * 4 + e)) * 4096 + scl) * 64 + d]
                               : &initV[((size_t)e * 32 + (s + 32)) * 64 + d];
    f4 kv = *(const f4*)pK;
    f4 vv = *(const f4*)pV;
    if (u == 63) { kv = make_float4(0.f,0.f,0.f,0.f); vv = make_float4(0.f,0.f,0.f,0.f); }
    uint2 kp; kp.x = pk2(kv.x, kv.y); kp.y = pk2(kv.z, kv.w);
    int ka = (u * 128 + d * 2) ^ ((u & 7) << 4);
    *(uint2*)((char*)&Kw[e][0] + ka) = kp;
    ushort vb[4] = { f2bf(vv.x), f2bf(vv.y), f2bf(vv.z), f2bf(vv.w) };
#pragma unroll
    for (int q = 0; q < 4; q++) {
      int dq = d + q;
      int va = (dq * 128 + u * 2) ^ ((dq & 7) << 4);
      *(ushort*)((char*)&Vt[e][0] + va) = vb[q];
    }
  }
  __syncthreads();

  floatx4 Yacc[4][4];
#pragma unroll
  for (int mi = 0; mi < 4; mi++)
#pragma unroll
    for (int nd = 0; nd < 4; nd++) Yacc[mi][nd] = (floatx4){0.f,0.f,0.f,0.f};
  float mrun[4][4], lrun[4][4];
#pragma unroll
  for (int mi = 0; mi < 4; mi++)
#pragma unroll
    for (int r = 0; r < 4; r++) { mrun[mi][r] = -1e30f; lrun[mi][r] = 0.f; }

  const floatx4 zf = (floatx4){0.f,0.f,0.f,0.f};
  char* pb = (char*)&Pl[w][0];

#pragma unroll
  for (int half = 0; half < 2; half++) {
    floatx4 S[2][4][4];
#pragma unroll
    for (int ep = 0; ep < 2; ep++) {
      const int e = half * 2 + ep;
#pragma unroll
      for (int ni = 0; ni < 4; ni++) {
        const int urow = ni * 16 + l15;
        const int sw = (urow & 7) << 4;
        short8 kf0 = *(const short8*)((const char*)&Kw[e][0] + ((urow * 128 + lg * 16) ^ sw));
        short8 kf1 = *(const short8*)((const char*)&Kw[e][0] + ((urow * 128 + 64 + lg * 16) ^ sw));
#pragma unroll
        for (int mi = 0; mi < 4; mi++) {
          floatx4 t_ = __builtin_amdgcn_mfma_f32_16x16x32_bf16(qf[mi][0], kf0, zf, 0, 0, 0);
          S[ep][mi][ni] = __builtin_amdgcn_mfma_f32_16x16x32_bf16(qf[mi][1], kf1, t_, 0, 0, 0);
        }
      }
    }
#pragma unroll
    for (int mi = 0; mi < 4; mi++)
#pragma unroll
      for (int r = 0; r < 4; r++) {
        const int iq = (mi & 1) * 16 + lg * 4 + r;
        float mx = mrun[mi][r];
#pragma unroll
        for (int ep = 0; ep < 2; ep++)
#pragma unroll
          for (int ni = 0; ni < 4; ni++) {
            const int u = ni * 16 + l15;
            float v = ((unsigned)(u - iq) < 32u) ? S[ep][mi][ni][r] : -1e30f;
            S[ep][mi][ni][r] = v;
            mx = fmaxf(mx, v);
          }
        mx = fmaxf(mx, __shfl_xor(mx, 1));
        mx = fmaxf(mx, __shfl_xor(mx, 2));
        mx = fmaxf(mx, __shfl_xor(mx, 4));
        mx = fmaxf(mx, __shfl_xor(mx, 8));
        float sc = __expf(mrun[mi][r] - mx);
        mrun[mi][r] = mx;
        float sum = 0.f;
#pragma unroll
        for (int ep = 0; ep < 2; ep++)
#pragma unroll
          for (int ni = 0; ni < 4; ni++) {
            float p = __expf(S[ep][mi][ni][r] - mx);
            S[ep][mi][ni][r] = p;
            sum += p;
          }
        sum += __shfl_xor(sum, 1);
        sum += __shfl_xor(sum, 2);
        sum += __shfl_xor(sum, 4);
        sum += __shfl_xor(sum, 8);
        lrun[mi][r] = lrun[mi][r] * sc + sum;
#pragma unroll
        for (int nd = 0; nd < 4; nd++) Yacc[mi][nd][r] *= sc;
      }
#pragma unroll
    for (int ep = 0; ep < 2; ep++) {
      const int e = half * 2 + ep;
#pragma unroll
      for (int mi = 0; mi < 4; mi++)
#pragma unroll
        for (int r = 0; r < 4; r++) {
          const int m = mi * 16 + lg * 4 + r;
          const int base = m * 128, sw = (m & 7) << 4;
#pragma unroll
          for (int ni = 0; ni < 4; ni++) {
            const int u = ni * 16 + l15;
            *(ushort*)(pb + ((base + u * 2) ^ sw)) = f2bf(S[ep][mi][ni][r]);
          }
        }
      asm volatile("s_waitcnt lgkmcnt(0)" ::: "memory");
      __builtin_amdgcn_sched_barrier(0);
#pragma unroll
      for (int kk = 0; kk < 2; kk++) {
        short8 pa[4];
#pragma unroll
        for (int mi = 0; mi < 4; mi++) {
          const int m = mi * 16 + l15;
          pa[mi] = *(const short8*)(pb + ((m * 128 + kk * 64 + lg * 16) ^ ((m & 7) << 4)));
        }
#pragma unroll
        for (int nd = 0; nd < 4; nd++) {
          const int dr = nd * 16 + l15;
          short8 vf = *(const short8*)((const char*)&Vt[e][0] +
                        ((dr * 128 + kk * 64 + lg * 16) ^ ((dr & 7) << 4)));
#pragma unroll
          for (int mi = 0; mi < 4; mi++)
            Yacc[mi][nd] = __builtin_amdgcn_mfma_f32_16x16x32_bf16(pa[mi], vf, Yacc[mi][nd], 0, 0, 0);
        }
      }
    }
  }

#pragma unroll
  for (int mi = 0; mi < 4; mi++)
#pragma unroll
    for (int r = 0; r < 4; r++) {
      const float inv = 1.f / lrun[mi][r];
      const int m = w * 64 + mi * 16 + lg * 4 + r;
      const int t = t0 + (m & 31), h = m >> 5;
      ushort* dst = &Yout[((size_t)(n * 4096 + t)) * 512 + h * 64];
#pragma unroll
      for (int nd = 0; nd < 4; nd++)
        dst[nd * 16 + l15] = f2bf(Yacc[mi][nd][r] * inv);
    }
}

extern "C" void kernel_launch(void* const* d_in, const int* in_sizes, int n_in,
                              void* d_out, int out_size, void* d_ws, size_t ws_size,
                              hipStream_t stream) {
  const float* X     = (const float*)d_in[0];
  const float* wG    = (const float*)d_in[1];
  const float* bG    = (const float*)d_in[2];
  const float* wK    = (const float*)d_in[3];
  const float* wV    = (const float*)d_in[4];
  const float* wQ    = (const float*)d_in[5];
  const float* wO    = (const float*)d_in[6];
  const float* initK = (const float*)d_in[7];
  const float* initV = (const float*)d_in[8];
  float* out = (float*)d_out;

  float* ws = (float*)d_ws;
  ushort* Xbf  = (ushort*)(ws + 0);
  float*  gK   = ws + 0;
  float*  gV   = ws + 2097152;
  ushort* wAll = (ushort*)(ws + 4194304);     // 1792x1024 bf16
  ushort* wObf = (ushort*)(ws + 5111808);     // 1024x512 bf16
  float*  Glin = ws + 5373952;                // 8192x32 f32
  float*  Kp   = ws + 5636096;                // 8192x512 f32 -> later Ybf (bf16)
  ushort* Ybf  = (ushort*)Kp;
  float*  Vp   = ws + 9830400;                // 8192x512 f32
  ushort* Qbf  = (ushort*)(ws + 14024704);    // 8192x512 bf16 (pre-scaled 1/8)
  float*  Aarr = ws + 16121856;               // 2*4*4096

  conv_f32_bf16<<<2048, 256, 0, stream>>>(X, Xbf, 2097152);
  conv_weights<<<1792, 256, 0, stream>>>(wK, wV, wQ, wG, wAll);
  transpose_wO<<<2048, 256, 0, stream>>>(wO, wObf);
  proj_gemm_256<<<224, 512, 0, stream>>>(Xbf, wAll, Kp, Vp, Qbf, Glin);
  gate_kernel<<<2048, 256, 0, stream>>>(Glin, bG, Kp, Vp, gK, gV, Aarr);
  scan_kernel<<<512, 64, 0, stream>>>(gK, gV, Aarr, initK, initV);
  attn_mfma<<<256, 256, 0, stream>>>(Qbf, gK, gV, initK, initV, Ybf);
  out_gemm_256<<<256, 512, 0, stream>>>(Ybf, wObf, out);
}

// Round 7
// 221.053 us; speedup vs baseline: 3.1839x; 1.0070x over previous
//
#include <hip/hip_runtime.h>
#include <hip/hip_bf16.h>

// Caterpillar: N=2 T=4096 D=1024 H=8 E=4 L=32 DK=DV=64
// R7: GEMMs back to 128^2 tiles (3 blocks/CU TLP) + ring-3 LDS, counted vmcnt(4),
//     single barrier/step, setprio, and 2-way-free chunk-XOR LDS swizzle
//     (pre-swizzled gll16 source + matching frag-read offset).
//     gate/scan/attn unchanged from passing R6.

using f4 = float4;
typedef __attribute__((ext_vector_type(8))) short short8;   // 8 bf16
typedef __attribute__((ext_vector_type(4))) float floatx4;  // 4 fp32 acc

__device__ __forceinline__ ushort f2bf(float x) {
  unsigned u = __float_as_uint(x);
  u += 0x7fffu + ((u >> 16) & 1u);   // RNE
  return (ushort)(u >> 16);
}
__device__ __forceinline__ unsigned pk2(float lo, float hi) {
  return (unsigned)f2bf(lo) | ((unsigned)f2bf(hi) << 16);
}

__device__ __forceinline__ void gll16(const void* g, void* l) {
  __builtin_amdgcn_global_load_lds((const __attribute__((address_space(1))) void*)g,
                                   (__attribute__((address_space(3))) void*)l, 16, 0, 0);
}

// ---------------- conversions ----------------
__global__ __launch_bounds__(256)
void conv_f32_bf16(const float* __restrict__ src, ushort* __restrict__ dst, int n4) {
  for (int i = blockIdx.x * blockDim.x + threadIdx.x; i < n4; i += gridDim.x * blockDim.x) {
    f4 v = ((const f4*)src)[i];
    ushort4 o; o.x = f2bf(v.x); o.y = f2bf(v.y); o.z = f2bf(v.z); o.w = f2bf(v.w);
    ((ushort4*)dst)[i] = o;
  }
}

// wAll rows: [0,512)=wK, [512,1024)=wV, [1024,1536)=wQ, [1536,1568)=wG, [1568,1664)=0
__global__ __launch_bounds__(256)
void conv_weights(const float* __restrict__ wK, const float* __restrict__ wV,
                  const float* __restrict__ wQ, const float* __restrict__ wG,
                  ushort* __restrict__ wAll) {
  int i4 = blockIdx.x * 256 + threadIdx.x;     // 0..425983
  int idx = i4 * 4;
  int row = idx >> 10;
  f4 v = make_float4(0.f, 0.f, 0.f, 0.f);
  if (row < 512)       v = *(const f4*)&wK[idx];
  else if (row < 1024) v = *(const f4*)&wV[idx - 524288];
  else if (row < 1536) v = *(const f4*)&wQ[idx - 1048576];
  else if (row < 1568) v = *(const f4*)&wG[idx - 1572864];
  ushort4 o; o.x = f2bf(v.x); o.y = f2bf(v.y); o.z = f2bf(v.z); o.w = f2bf(v.w);
  *(ushort4*)&wAll[idx] = o;
}

__global__ __launch_bounds__(256)
void transpose_wO(const float* __restrict__ wO, ushort* __restrict__ wObf) {
  int i = blockIdx.x * 256 + threadIdx.x;
  int n = i >> 9, k = i & 511;
  wObf[i] = f2bf(wO[(size_t)k * 1024 + n]);
}

// ---------------- 128^2 GEMM step (ring-3, swizzled) ----------------
// LDS slot: 128 rows x 32 k (bf16) = 8KB, phys_chunk = chunk ^ (r&3) ^ ((r>>2)&3).
// Staging: linear gll16 dest, pre-swizzled global source. Reads apply same XOR.
#define GSTEP(LDA_, WAITS, STAGE_, KT) do {                                       \
  asm volatile("s_waitcnt vmcnt(" WAITS ")" ::: "memory");                        \
  __builtin_amdgcn_s_barrier();                                                   \
  if (STAGE_) {                                                                   \
    const ushort* ga = gA + (size_t)((KT) + 2) * 32;                              \
    const ushort* gb = gB + (size_t)((KT) + 2) * 32;                              \
    ushort* la = As + ss * 4096 + tid * 8;                                        \
    ushort* lb = Bs + ss * 4096 + tid * 8;                                        \
    gll16(ga, la); gll16(ga + 64 * (LDA_), la + 2048);                            \
    gll16(gb, lb); gll16(gb + 64 * (LDA_), lb + 2048);                            \
  }                                                                               \
  {                                                                               \
    const ushort* Afp = As + cs * 4096 + (wm + l15) * 32 + koff;                  \
    const ushort* Bfp = Bs + cs * 4096 + (wn + l15) * 32 + koff;                  \
    short8 bf_[4];                                                                \
    _Pragma("unroll")                                                             \
    for (int ni = 0; ni < 4; ni++) bf_[ni] = *(const short8*)(Bfp + ni * 512);    \
    __builtin_amdgcn_s_setprio(1);                                                \
    _Pragma("unroll")                                                             \
    for (int mi = 0; mi < 4; mi++) {                                              \
      short8 af_ = *(const short8*)(Afp + mi * 512);                              \
      _Pragma("unroll")                                                           \
      for (int ni = 0; ni < 4; ni++)                                              \
        acc[mi][ni] = __builtin_amdgcn_mfma_f32_16x16x32_bf16(                    \
            af_, bf_[ni], acc[mi][ni], 0, 0, 0);                                  \
    }                                                                             \
    __builtin_amdgcn_s_setprio(0);                                                \
    cs = (cs == 2) ? 0 : cs + 1;                                                  \
    ss = (ss == 2) ? 0 : ss + 1;                                                  \
  }                                                                               \
} while (0)

// ---------------- projection GEMM ----------------
// C[m,f] = sum_k Xbf[m,k]*wAll[f,k]; grid 832 = 8 XCD x (13 ct x 8 my).
__global__ __launch_bounds__(256, 3)
void proj_gemm_128s(const ushort* __restrict__ Xbf, const ushort* __restrict__ wAll,
                    float* __restrict__ Kp, float* __restrict__ Vp,
                    ushort* __restrict__ Qbf, float* __restrict__ Glin)
{
  __shared__ ushort As[3 * 4096];   // ring-3: 128x32 bf16 per slot
  __shared__ ushort Bs[3 * 4096];

  const int tid = threadIdx.x;
  const int bid = blockIdx.x;               // 0..831
  const int xcd = bid & 7, slot = bid >> 3; // slot 0..103
  const int ct = slot % 13;                 // col-tile 0..12
  const int my = xcd * 8 + slot / 13;       // 0..63
  const int m0 = my * 128, n0 = ct * 128;

  const int lane = tid & 63, w = tid >> 6;
  const int wm = (w >> 1) * 64, wn = (w & 1) * 64;
  const int l15 = lane & 15, lg = lane >> 4;
  const int fl = (l15 & 3) ^ ((l15 >> 2) & 3);
  const int koff = ((lg ^ fl) & 3) * 8;

  const int srow = tid >> 2;
  const int schunk = (tid & 3) ^ ((srow & 3) ^ ((srow >> 2) & 3));
  const ushort* gA = Xbf  + (size_t)(m0 + srow) * 1024 + schunk * 8;
  const ushort* gB = wAll + (size_t)(n0 + srow) * 1024 + schunk * 8;

  floatx4 acc[4][4];
#pragma unroll
  for (int mi = 0; mi < 4; mi++)
#pragma unroll
    for (int ni = 0; ni < 4; ni++) acc[mi][ni] = (floatx4){0.f, 0.f, 0.f, 0.f};

  // prologue: stage slots 0,1
#pragma unroll
  for (int t_ = 0; t_ < 2; t_++) {
    const ushort* ga = gA + t_ * 32;
    const ushort* gb = gB + t_ * 32;
    ushort* la = As + t_ * 4096 + tid * 8;
    ushort* lb = Bs + t_ * 4096 + tid * 8;
    gll16(ga, la); gll16(ga + 65536, la + 2048);
    gll16(gb, lb); gll16(gb + 65536, lb + 2048);
  }
  int cs = 0, ss = 2;

#pragma unroll 1
  for (int kt = 0; kt < 31; ++kt) GSTEP(1024, "4", kt <= 29, kt);
  GSTEP(1024, "0", false, 31);

  // epilogue: split columns K/V/Q/G
#pragma unroll
  for (int mi = 0; mi < 4; mi++) {
    const int rm = m0 + wm + mi * 16 + lg * 4;
#pragma unroll
    for (int ni = 0; ni < 4; ni++) {
      const int Cg = n0 + wn + ni * 16 + l15;
#pragma unroll
      for (int j = 0; j < 4; j++) {
        const float v = acc[mi][ni][j];
        if (Cg < 512)        Kp [(size_t)(rm + j) * 512 + Cg] = v;
        else if (Cg < 1024)  Vp [(size_t)(rm + j) * 512 + Cg - 512] = v;
        else if (Cg < 1536)  Qbf[(size_t)(rm + j) * 512 + Cg - 1024] = f2bf(v * 0.125f);
        else if (Cg < 1568)  Glin[(size_t)(rm + j) * 32 + Cg - 1536] = v;
      }
    }
  }
}

// ---------------- output GEMM: out = Ybf(8192x512) @ wObf^T ----------------
__global__ __launch_bounds__(256, 3)
void out_gemm_128s(const ushort* __restrict__ Ybf, const ushort* __restrict__ wObf,
                   float* __restrict__ out)
{
  __shared__ ushort As[3 * 4096];
  __shared__ ushort Bs[3 * 4096];

  const int tid = threadIdx.x;
  const int bid = blockIdx.x;               // 0..511
  const int xcd = bid & 7, slot = bid >> 3; // 0..63
  const int ct = slot & 7;                  // col-tile 0..7
  const int my = xcd * 8 + (slot >> 3);     // 0..63
  const int m0 = my * 128, n0 = ct * 128;

  const int lane = tid & 63, w = tid >> 6;
  const int wm = (w >> 1) * 64, wn = (w & 1) * 64;
  const int l15 = lane & 15, lg = lane >> 4;
  const int fl = (l15 & 3) ^ ((l15 >> 2) & 3);
  const int koff = ((lg ^ fl) & 3) * 8;

  const int srow = tid >> 2;
  const int schunk = (tid & 3) ^ ((srow & 3) ^ ((srow >> 2) & 3));
  const ushort* gA = Ybf  + (size_t)(m0 + srow) * 512 + schunk * 8;
  const ushort* gB = wObf + (size_t)(n0 + srow) * 512 + schunk * 8;

  floatx4 acc[4][4];
#pragma unroll
  for (int mi = 0; mi < 4; mi++)
#pragma unroll
    for (int ni = 0; ni < 4; ni++) acc[mi][ni] = (floatx4){0.f, 0.f, 0.f, 0.f};

#pragma unroll
  for (int t_ = 0; t_ < 2; t_++) {
    const ushort* ga = gA + t_ * 32;
    const ushort* gb = gB + t_ * 32;
    ushort* la = As + t_ * 4096 + tid * 8;
    ushort* lb = Bs + t_ * 4096 + tid * 8;
    gll16(ga, la); gll16(ga + 32768, la + 2048);
    gll16(gb, lb); gll16(gb + 32768, lb + 2048);
  }
  int cs = 0, ss = 2;

#pragma unroll 1
  for (int kt = 0; kt < 15; ++kt) GSTEP(512, "4", kt <= 13, kt);
  GSTEP(512, "0", false, 15);

#pragma unroll
  for (int mi = 0; mi < 4; mi++) {
    const int rm = m0 + wm + mi * 16 + lg * 4;
#pragma unroll
    for (int ni = 0; ni < 4; ni++) {
      const int cn = n0 + wn + ni * 16 + l15;
#pragma unroll
      for (int j = 0; j < 4; j++)
        out[(size_t)(rm + j) * 1024 + cn] = acc[mi][ni][j];
    }
  }
}

// ---------------- gate/mix ----------------
__global__ __launch_bounds__(256)
void gate_kernel(const float* __restrict__ Glin, const float* __restrict__ bG,
                 const float* __restrict__ Kp, const float* __restrict__ Vp,
                 float* __restrict__ gK, float* __restrict__ gV, float* __restrict__ Aout)
{
  const int nt = blockIdx.x * 4 + (threadIdx.x >> 6);
  const int lane = threadIdx.x & 63;
  const int n = nt >> 12;
  const int t = nt & 4095;

  float g[32];
  float gsum[4] = {0.f, 0.f, 0.f, 0.f};
#pragma unroll
  for (int f = 0; f < 32; f++) {
    float z = Glin[(size_t)nt * 32 + f] + bG[f];
    float s = 1.f / (1.f + __expf(-z));
    g[f] = s;
    gsum[f & 3] += s;
  }
  if (lane < 4) {
    float a = 1.f - fminf(gsum[lane], 1.f);
    Aout[(size_t)(n * 4 + lane) * 4096 + t] = a;
  }
  float gk[4] = {0.f, 0.f, 0.f, 0.f}, gv[4] = {0.f, 0.f, 0.f, 0.f};
#pragma unroll
  for (int h = 0; h < 8; h++) {
    float kv = Kp[(size_t)nt * 512 + h * 64 + lane];
    float vv = Vp[(size_t)nt * 512 + h * 64 + lane];
#pragma unroll
    for (int e = 0; e < 4; e++) {
      gk[e] = fmaf(g[h * 4 + e], kv, gk[e]);
      gv[e] = fmaf(g[h * 4 + e], vv, gv[e]);
    }
  }
#pragma unroll
  for (int e = 0; e < 4; e++) {
    size_t base = ((size_t)(n * 4 + e) * 4096 + t) * 64 + lane;
    gK[base] = gk[e];
    gV[base] = gv[e];
  }
}

// ---------------- chunked scan ----------------
__global__ __launch_bounds__(64)
void scan_kernel(float* __restrict__ gK, float* __restrict__ gV,
                 const float* __restrict__ Aarr,
                 const float* __restrict__ initK, const float* __restrict__ initV)
{
  __shared__ float sB[128 * 64];
  __shared__ float sA[128];
  const int b = blockIdx.x;
  const int half = b >> 8, sub = b & 255;
  float* gX = half ? gV : gK;
  const float* initX = half ? initV : initK;
  const int n = sub >> 7, r = sub & 127, e = r >> 5, l = r & 31;
  const int tbase = l * 128;
  const size_t base = ((size_t)(n * 4 + e) * 4096 + tbase) * 64;
  const int tid = threadIdx.x;

  const f4* src = (const f4*)&gX[base];
#pragma unroll
  for (int q = 0; q < 32; q++)
    *(f4*)&sB[(tid + q * 64) * 4] = src[tid + q * 64];
  sA[tid]      = Aarr[(size_t)(n * 4 + e) * 4096 + tbase + tid];
  sA[64 + tid] = Aarr[(size_t)(n * 4 + e) * 4096 + tbase + 64 + tid];
  __syncthreads();

  float state = initX[((size_t)e * 32 + l) * 64 + tid];
  float* dst = &gX[base];
  for (int c = 0; c < 128; c++) {
    state = fmaf(sA[c], state, sB[c * 64 + tid]);
    dst[c * 64 + tid] = state;
  }
}

// ---------------- MFMA window attention (Q pre-scaled bf16) ----------------
__global__ __launch_bounds__(256, 1)
void attn_mfma(const ushort* __restrict__ Qbf, const float* __restrict__ nK,
               const float* __restrict__ nV, const float* __restrict__ initK,
               const float* __restrict__ initV, ushort* __restrict__ Yout)
{
  __shared__ ushort Kw[4][4096];   // [e][u*64+d] bf16, byte-addr ^ ((u&7)<<4)
  __shared__ ushort Vt[4][4096];   // [e][d*64+u] bf16, byte-addr ^ ((d&7)<<4)
  __shared__ ushort Pl[4][4096];   // per-wave P [m*64+u],  ^ ((m&7)<<4)

  const int blk = blockIdx.x;
  const int n = blk >> 7, c = blk & 127;
  const int t0 = c * 32;
  const int tid = threadIdx.x;
  const int lane = tid & 63;
  const int w = tid >> 6;
  const int l15 = lane & 15, lg = lane >> 4;

  short8 qf[4][2];
#pragma unroll
  for (int mi = 0; mi < 4; mi++) {
    int m = w * 64 + mi * 16 + l15;
    int t = t0 + (m & 31), h = m >> 5;
    const ushort* src = &Qbf[((size_t)(n * 4096 + t)) * 512 + h * 64];
#pragma unroll
    for (int kk = 0; kk < 2; kk++)
      qf[mi][kk] = *(const short8*)&src[kk * 32 + lg * 8];
  }

#pragma unroll 4
  for (int it = 0; it < 16; it++) {
    int idx = it * 256 + tid;
    int e = idx >> 10, u = (idx >> 4) & 63, d = (idx & 15) * 4;
    int s = t0 - 31 + u;
    int scl = s < 4095 ? s : 4095;
    const float* pK = (s >= 0) ? &nK[(((size_t)(n * 4 + e)) * 4096 + scl) * 64 + d]
                               : &initK[((size_t)e * 32 + (s + 32)) * 64 + d];
    const float* pV = (s >= 0) ? &nV[(((size_t)(n * 4 + e)) * 4096 + scl) * 64 + d]
                               : &initV[((size_t)e * 32 + (s + 32)) * 64 + d];
    f4 kv = *(const f4*)pK;
    f4 vv = *(const f4*)pV;
    if (u == 63) { kv = make_float4(0.f,0.f,0.f,0.f); vv = make_float4(0.f,0.f,0.f,0.f); }
    uint2 kp; kp.x = pk2(kv.x, kv.y); kp.y = pk2(kv.z, kv.w);
    int ka = (u * 128 + d * 2) ^ ((u & 7) << 4);
    *(uint2*)((char*)&Kw[e][0] + ka) = kp;
    ushort vb[4] = { f2bf(vv.x), f2bf(vv.y), f2bf(vv.z), f2bf(vv.w) };
#pragma unroll
    for (int q = 0; q < 4; q++) {
      int dq = d + q;
      int va = (dq * 128 + u * 2) ^ ((dq & 7) << 4);
      *(ushort*)((char*)&Vt[e][0] + va) = vb[q];
    }
  }
  __syncthreads();

  floatx4 Yacc[4][4];
#pragma unroll
  for (int mi = 0; mi < 4; mi++)
#pragma unroll
    for (int nd = 0; nd < 4; nd++) Yacc[mi][nd] = (floatx4){0.f,0.f,0.f,0.f};
  float mrun[4][4], lrun[4][4];
#pragma unroll
  for (int mi = 0; mi < 4; mi++)
#pragma unroll
    for (int r = 0; r < 4; r++) { mrun[mi][r] = -1e30f; lrun[mi][r] = 0.f; }

  const floatx4 zf = (floatx4){0.f,0.f,0.f,0.f};
  char* pb = (char*)&Pl[w][0];

#pragma unroll
  for (int half = 0; half < 2; half++) {
    floatx4 S[2][4][4];
#pragma unroll
    for (int ep = 0; ep < 2; ep++) {
      const int e = half * 2 + ep;
#pragma unroll
      for (int ni = 0; ni < 4; ni++) {
        const int urow = ni * 16 + l15;
        const int sw = (urow & 7) << 4;
        short8 kf0 = *(const short8*)((const char*)&Kw[e][0] + ((urow * 128 + lg * 16) ^ sw));
        short8 kf1 = *(const short8*)((const char*)&Kw[e][0] + ((urow * 128 + 64 + lg * 16) ^ sw));
#pragma unroll
        for (int mi = 0; mi < 4; mi++) {
          floatx4 t_ = __builtin_amdgcn_mfma_f32_16x16x32_bf16(qf[mi][0], kf0, zf, 0, 0, 0);
          S[ep][mi][ni] = __builtin_amdgcn_mfma_f32_16x16x32_bf16(qf[mi][1], kf1, t_, 0, 0, 0);
        }
      }
    }
#pragma unroll
    for (int mi = 0; mi < 4; mi++)
#pragma unroll
      for (int r = 0; r < 4; r++) {
        const int iq = (mi & 1) * 16 + lg * 4 + r;
        float mx = mrun[mi][r];
#pragma unroll
        for (int ep = 0; ep < 2; ep++)
#pragma unroll
          for (int ni = 0; ni < 4; ni++) {
            const int u = ni * 16 + l15;
            float v = ((unsigned)(u - iq) < 32u) ? S[ep][mi][ni][r] : -1e30f;
            S[ep][mi][ni][r] = v;
            mx = fmaxf(mx, v);
          }
        mx = fmaxf(mx, __shfl_xor(mx, 1));
        mx = fmaxf(mx, __shfl_xor(mx, 2));
        mx = fmaxf(mx, __shfl_xor(mx, 4));
        mx = fmaxf(mx, __shfl_xor(mx, 8));
        float sc = __expf(mrun[mi][r] - mx);
        mrun[mi][r] = mx;
        float sum = 0.f;
#pragma unroll
        for (int ep = 0; ep < 2; ep++)
#pragma unroll
          for (int ni = 0; ni < 4; ni++) {
            float p = __expf(S[ep][mi][ni][r] - mx);
            S[ep][mi][ni][r] = p;
            sum += p;
          }
        sum += __shfl_xor(sum, 1);
        sum += __shfl_xor(sum, 2);
        sum += __shfl_xor(sum, 4);
        sum += __shfl_xor(sum, 8);
        lrun[mi][r] = lrun[mi][r] * sc + sum;
#pragma unroll
        for (int nd = 0; nd < 4; nd++) Yacc[mi][nd][r] *= sc;
      }
#pragma unroll
    for (int ep = 0; ep < 2; ep++) {
      const int e = half * 2 + ep;
#pragma unroll
      for (int mi = 0; mi < 4; mi++)
#pragma unroll
        for (int r = 0; r < 4; r++) {
          const int m = mi * 16 + lg * 4 + r;
          const int base = m * 128, sw = (m & 7) << 4;
#pragma unroll
          for (int ni = 0; ni < 4; ni++) {
            const int u = ni * 16 + l15;
            *(ushort*)(pb + ((base + u * 2) ^ sw)) = f2bf(S[ep][mi][ni][r]);
          }
        }
      asm volatile("s_waitcnt lgkmcnt(0)" ::: "memory");
      __builtin_amdgcn_sched_barrier(0);
#pragma unroll
      for (int kk = 0; kk < 2; kk++) {
        short8 pa[4];
#pragma unroll
        for (int mi = 0; mi < 4; mi++) {
          const int m = mi * 16 + l15;
          pa[mi] = *(const short8*)(pb + ((m * 128 + kk * 64 + lg * 16) ^ ((m & 7) << 4)));
        }
#pragma unroll
        for (int nd = 0; nd < 4; nd++) {
          const int dr = nd * 16 + l15;
          short8 vf = *(const short8*)((const char*)&Vt[e][0] +
                        ((dr * 128 + kk * 64 + lg * 16) ^ ((dr & 7) << 4)));
#pragma unroll
          for (int mi = 0; mi < 4; mi++)
            Yacc[mi][nd] = __builtin_amdgcn_mfma_f32_16x16x32_bf16(pa[mi], vf, Yacc[mi][nd], 0, 0, 0);
        }
      }
    }
  }

#pragma unroll
  for (int mi = 0; mi < 4; mi++)
#pragma unroll
    for (int r = 0; r < 4; r++) {
      const float inv = 1.f / lrun[mi][r];
      const int m = w * 64 + mi * 16 + lg * 4 + r;
      const int t = t0 + (m & 31), h = m >> 5;
      ushort* dst = &Yout[((size_t)(n * 4096 + t)) * 512 + h * 64];
#pragma unroll
      for (int nd = 0; nd < 4; nd++)
        dst[nd * 16 + l15] = f2bf(Yacc[mi][nd][r] * inv);
    }
}

extern "C" void kernel_launch(void* const* d_in, const int* in_sizes, int n_in,
                              void* d_out, int out_size, void* d_ws, size_t ws_size,
                              hipStream_t stream) {
  const float* X     = (const float*)d_in[0];
  const float* wG    = (const float*)d_in[1];
  const float* bG    = (const float*)d_in[2];
  const float* wK    = (const float*)d_in[3];
  const float* wV    = (const float*)d_in[4];
  const float* wQ    = (const float*)d_in[5];
  const float* wO    = (const float*)d_in[6];
  const float* initK = (const float*)d_in[7];
  const float* initV = (const float*)d_in[8];
  float* out = (float*)d_out;

  float* ws = (float*)d_ws;
  ushort* Xbf  = (ushort*)(ws + 0);
  float*  gK   = ws + 0;
  float*  gV   = ws + 2097152;
  ushort* wAll = (ushort*)(ws + 4194304);     // 1664x1024 bf16
  ushort* wObf = (ushort*)(ws + 5111808);     // 1024x512 bf16
  float*  Glin = ws + 5373952;                // 8192x32 f32
  float*  Kp   = ws + 5636096;                // 8192x512 f32 -> later Ybf (bf16)
  ushort* Ybf  = (ushort*)Kp;
  float*  Vp   = ws + 9830400;                // 8192x512 f32
  ushort* Qbf  = (ushort*)(ws + 14024704);    // 8192x512 bf16 (pre-scaled 1/8)
  float*  Aarr = ws + 16121856;               // 2*4*4096

  conv_f32_bf16<<<2048, 256, 0, stream>>>(X, Xbf, 2097152);
  conv_weights<<<1664, 256, 0, stream>>>(wK, wV, wQ, wG, wAll);
  transpose_wO<<<2048, 256, 0, stream>>>(wO, wObf);
  proj_gemm_128s<<<832, 256, 0, stream>>>(Xbf, wAll, Kp, Vp, Qbf, Glin);
  gate_kernel<<<2048, 256, 0, stream>>>(Glin, bG, Kp, Vp, gK, gV, Aarr);
  scan_kernel<<<512, 64, 0, stream>>>(gK, gV, Aarr, initK, initV);
  attn_mfma<<<256, 256, 0, stream>>>(Qbf, gK, gV, initK, initV, Ybf);
  out_gemm_128s<<<512, 256, 0, stream>>>(Ybf, wObf, out);
}